// Round 1
// baseline (1658.492 us; speedup 1.0000x reference)
//
#include <hip/hip_runtime.h>
#include <math.h>

#define DIMV 2048
#define NHEAD 16
#define NKV 8
#define HD 128
#define BATCH 2
#define SEQ 2048
#define CHUNK 128
#define NCHUNK 16
#define MTOK 4096  // BATCH*SEQ

// ---------------------------------------------------------------------------
// Generic tiled SGEMM: C[M,N] = A[M,K] @ B[N,K]^T   (both row-major)
// 128x128 C-tile per 256-thread block, 8x8 per thread, K-tile 16.
// ---------------------------------------------------------------------------
__global__ __launch_bounds__(256) void gemm_bt(const float* __restrict__ A,
                                               const float* __restrict__ Bm,
                                               float* __restrict__ C,
                                               int M, int N, int K) {
  __shared__ float As[16][132];
  __shared__ float Bs[16][132];
  const int tid = threadIdx.x;
  const int tx = tid & 15, ty = tid >> 4;
  const int row0 = blockIdx.y * 128, col0 = blockIdx.x * 128;
  float acc[8][8];
#pragma unroll
  for (int i = 0; i < 8; ++i)
#pragma unroll
    for (int j = 0; j < 8; ++j) acc[i][j] = 0.f;

  for (int k0 = 0; k0 < K; k0 += 16) {
#pragma unroll
    for (int i = 0; i < 2; ++i) {
      int lin = tid + i * 256;          // 0..511 float4 slots
      int r = lin >> 2, kq = lin & 3;
      float4 va = *(const float4*)&A[(size_t)(row0 + r) * K + k0 + kq * 4];
      As[kq * 4 + 0][r] = va.x; As[kq * 4 + 1][r] = va.y;
      As[kq * 4 + 2][r] = va.z; As[kq * 4 + 3][r] = va.w;
      float4 vb = *(const float4*)&Bm[(size_t)(col0 + r) * K + k0 + kq * 4];
      Bs[kq * 4 + 0][r] = vb.x; Bs[kq * 4 + 1][r] = vb.y;
      Bs[kq * 4 + 2][r] = vb.z; Bs[kq * 4 + 3][r] = vb.w;
    }
    __syncthreads();
#pragma unroll
    for (int kk = 0; kk < 16; ++kk) {
      float4 a0 = *(const float4*)&As[kk][ty * 8];
      float4 a1 = *(const float4*)&As[kk][ty * 8 + 4];
      float4 b0 = *(const float4*)&Bs[kk][tx * 8];
      float4 b1 = *(const float4*)&Bs[kk][tx * 8 + 4];
      float a[8] = {a0.x, a0.y, a0.z, a0.w, a1.x, a1.y, a1.z, a1.w};
      float b[8] = {b0.x, b0.y, b0.z, b0.w, b1.x, b1.y, b1.z, b1.w};
#pragma unroll
      for (int i = 0; i < 8; ++i)
#pragma unroll
        for (int j = 0; j < 8; ++j) acc[i][j] += a[i] * b[j];
    }
    __syncthreads();
  }
#pragma unroll
  for (int i = 0; i < 8; ++i) {
    int r = row0 + ty * 8 + i;
#pragma unroll
    for (int jq = 0; jq < 2; ++jq) {
      float4 v = make_float4(acc[i][jq * 4], acc[i][jq * 4 + 1],
                             acc[i][jq * 4 + 2], acc[i][jq * 4 + 3]);
      *(float4*)&C[(size_t)r * N + col0 + tx * 8 + jq * 4] = v;
    }
  }
}

// ---------------------------------------------------------------------------
// RoPE + row softmax (scale D^-0.5) on q. One 64-lane wave per (token, head).
// grid = MTOK*NHEAD, block = 64. Lane t owns pair (2t, 2t+1) of the 128 dims.
// ---------------------------------------------------------------------------
__global__ __launch_bounds__(64) void rope_q_softmax(float* __restrict__ q,
                                                     const float* __restrict__ fc) {
  int bi = blockIdx.x;
  int h = bi & (NHEAD - 1), m = bi >> 4;
  int s = m & (SEQ - 1);
  int t = threadIdx.x;
  size_t base = (size_t)m * DIMV + h * HD + 2 * t;
  float2 xv = *(const float2*)&q[base];
  float2 cs = *(const float2*)&fc[s * HD + 2 * t];
  float o0 = xv.x * cs.x - xv.y * cs.y;
  float o1 = xv.x * cs.y + xv.y * cs.x;
  const float sc = 0.08838834764831845f;  // 128^-0.5
  o0 *= sc; o1 *= sc;
  float mx = fmaxf(o0, o1);
#pragma unroll
  for (int off = 1; off < 64; off <<= 1) mx = fmaxf(mx, __shfl_xor(mx, off));
  float e0 = __expf(o0 - mx) , e1 = __expf(o1 - mx);
  // use precise expf for accuracy margin
  e0 = expf(o0 - mx); e1 = expf(o1 - mx);
  float sm = e0 + e1;
#pragma unroll
  for (int off = 1; off < 64; off <<= 1) sm += __shfl_xor(sm, off);
  float inv = 1.f / sm;
  *(float2*)&q[base] = make_float2(e0 * inv, e1 * inv);
}

// RoPE only on k. grid = MTOK*NKV, block = 64.
__global__ __launch_bounds__(64) void rope_k(float* __restrict__ k,
                                             const float* __restrict__ fc) {
  int bi = blockIdx.x;
  int h = bi & (NKV - 1), m = bi >> 3;
  int s = m & (SEQ - 1);
  int t = threadIdx.x;
  size_t base = (size_t)m * (NKV * HD) + h * HD + 2 * t;
  float2 xv = *(const float2*)&k[base];
  float2 cs = *(const float2*)&fc[s * HD + 2 * t];
  *(float2*)&k[base] = make_float2(xv.x * cs.x - xv.y * cs.y,
                                   xv.x * cs.y + xv.y * cs.x);
}

// ---------------------------------------------------------------------------
// Column softmax over the SEQ axis per (batch, col), col in [0,1024).
// grid = BATCH*1024 blocks, 256 threads; each thread covers 8 rows.
// ---------------------------------------------------------------------------
__global__ __launch_bounds__(256) void kcol_softmax(float* __restrict__ k) {
  int b = blockIdx.x >> 10, col = blockIdx.x & 1023;
  int tid = threadIdx.x;
  __shared__ float red[4];
  float vals[8];
  float mx = -1e30f;
#pragma unroll
  for (int i = 0; i < 8; ++i) {
    int s = tid + i * 256;
    vals[i] = k[(size_t)(b * SEQ + s) * (NKV * HD) + col];
    mx = fmaxf(mx, vals[i]);
  }
#pragma unroll
  for (int off = 1; off < 64; off <<= 1) mx = fmaxf(mx, __shfl_xor(mx, off));
  if ((tid & 63) == 0) red[tid >> 6] = mx;
  __syncthreads();
  if (tid == 0) red[0] = fmaxf(fmaxf(red[0], red[1]), fmaxf(red[2], red[3]));
  __syncthreads();
  mx = red[0];
  float sm = 0.f;
#pragma unroll
  for (int i = 0; i < 8; ++i) { vals[i] = expf(vals[i] - mx); sm += vals[i]; }
#pragma unroll
  for (int off = 1; off < 64; off <<= 1) sm += __shfl_xor(sm, off);
  __syncthreads();  // everyone has read red[0]
  if ((tid & 63) == 0) red[tid >> 6] = sm;
  __syncthreads();
  if (tid == 0) red[0] = red[0] + red[1] + red[2] + red[3];
  __syncthreads();
  float inv = 1.f / red[0];
#pragma unroll
  for (int i = 0; i < 8; ++i) {
    int s = tid + i * 256;
    k[(size_t)(b * SEQ + s) * (NKV * HD) + col] = vals[i] * inv;
  }
}

// ---------------------------------------------------------------------------
// Per-chunk kv[d,e] = sum_c ks[c,d]*v[c,e].  One block per (b,kvh,n).
// ---------------------------------------------------------------------------
__global__ __launch_bounds__(256) void kv_chunk(const float* __restrict__ k,
                                                const float* __restrict__ v,
                                                float* __restrict__ kvc) {
  int bi = blockIdx.x;  // (b*8+kvh)*16 + n
  int n = bi & 15, kvh = (bi >> 4) & 7, b = bi >> 7;
  int rowbase = b * SEQ + n * CHUNK;
  int colbase = kvh * HD;
  __shared__ float Ks[16][132], Vs[16][132];
  int tid = threadIdx.x, tx = tid & 15, ty = tid >> 4;
  float acc[8][8];
#pragma unroll
  for (int i = 0; i < 8; ++i)
#pragma unroll
    for (int j = 0; j < 8; ++j) acc[i][j] = 0.f;

  for (int c0 = 0; c0 < CHUNK; c0 += 16) {
#pragma unroll
    for (int i = 0; i < 2; ++i) {
      int lin = tid + i * 256;
      int cc = lin >> 5, cq = lin & 31;
      size_t g = (size_t)(rowbase + c0 + cc) * (NKV * HD) + colbase + cq * 4;
      *(float4*)&Ks[cc][cq * 4] = *(const float4*)&k[g];
      *(float4*)&Vs[cc][cq * 4] = *(const float4*)&v[g];
    }
    __syncthreads();
#pragma unroll
    for (int cc = 0; cc < 16; ++cc) {
      float4 a0 = *(const float4*)&Ks[cc][ty * 8];
      float4 a1 = *(const float4*)&Ks[cc][ty * 8 + 4];
      float4 b0 = *(const float4*)&Vs[cc][tx * 8];
      float4 b1 = *(const float4*)&Vs[cc][tx * 8 + 4];
      float a[8] = {a0.x, a0.y, a0.z, a0.w, a1.x, a1.y, a1.z, a1.w};
      float bb[8] = {b0.x, b0.y, b0.z, b0.w, b1.x, b1.y, b1.z, b1.w};
#pragma unroll
      for (int i = 0; i < 8; ++i)
#pragma unroll
        for (int j = 0; j < 8; ++j) acc[i][j] += a[i] * bb[j];
    }
    __syncthreads();
  }
#pragma unroll
  for (int i = 0; i < 8; ++i) {
    int d = ty * 8 + i;
#pragma unroll
    for (int jq = 0; jq < 2; ++jq) {
      float4 vv = make_float4(acc[i][jq * 4], acc[i][jq * 4 + 1],
                              acc[i][jq * 4 + 2], acc[i][jq * 4 + 3]);
      *(float4*)&kvc[(size_t)bi * 16384 + d * 128 + tx * 8 + jq * 4] = vv;
    }
  }
}

// Exclusive cumsum over the 16 chunks, in place. grid = 1024 x 256 threads.
__global__ __launch_bounds__(256) void cumsum_excl(float* __restrict__ kvc) {
  int gid = blockIdx.x * 256 + threadIdx.x;  // 0..262143
  int bk = gid >> 14;       // b*8+kvh
  int idx = gid & 16383;
  size_t base = (size_t)bk * NCHUNK * 16384 + idx;
  float run = 0.f;
#pragma unroll
  for (int n = 0; n < NCHUNK; ++n) {
    float t = kvc[base + (size_t)n * 16384];
    kvc[base + (size_t)n * 16384] = run;
    run += t;
  }
}

// ---------------------------------------------------------------------------
// scores[c,m] = tril( sum_d qs[c,d]*ks[m,d] ).  One block per (b,h,n).
// ---------------------------------------------------------------------------
__global__ __launch_bounds__(256) void scores_nt(const float* __restrict__ q,
                                                 const float* __restrict__ k,
                                                 float* __restrict__ sc) {
  int bi = blockIdx.x;  // (b*16+h)*16+n
  int n = bi & 15, h = (bi >> 4) & 15, b = bi >> 8;
  int kvh = h >> 1;
  int rowbase = b * SEQ + n * CHUNK;
  __shared__ float As[16][132], Bs[16][132];
  int tid = threadIdx.x, tx = tid & 15, ty = tid >> 4;
  float acc[8][8];
#pragma unroll
  for (int i = 0; i < 8; ++i)
#pragma unroll
    for (int j = 0; j < 8; ++j) acc[i][j] = 0.f;

  for (int k0 = 0; k0 < HD; k0 += 16) {
#pragma unroll
    for (int i = 0; i < 2; ++i) {
      int lin = tid + i * 256;
      int r = lin >> 2, kq = lin & 3;
      float4 va = *(const float4*)&q[(size_t)(rowbase + r) * DIMV + h * HD + k0 + kq * 4];
      As[kq * 4 + 0][r] = va.x; As[kq * 4 + 1][r] = va.y;
      As[kq * 4 + 2][r] = va.z; As[kq * 4 + 3][r] = va.w;
      float4 vb = *(const float4*)&k[(size_t)(rowbase + r) * (NKV * HD) + kvh * HD + k0 + kq * 4];
      Bs[kq * 4 + 0][r] = vb.x; Bs[kq * 4 + 1][r] = vb.y;
      Bs[kq * 4 + 2][r] = vb.z; Bs[kq * 4 + 3][r] = vb.w;
    }
    __syncthreads();
#pragma unroll
    for (int kk = 0; kk < 16; ++kk) {
      float4 a0 = *(const float4*)&As[kk][ty * 8];
      float4 a1 = *(const float4*)&As[kk][ty * 8 + 4];
      float4 b0 = *(const float4*)&Bs[kk][tx * 8];
      float4 b1 = *(const float4*)&Bs[kk][tx * 8 + 4];
      float a[8] = {a0.x, a0.y, a0.z, a0.w, a1.x, a1.y, a1.z, a1.w};
      float bb[8] = {b0.x, b0.y, b0.z, b0.w, b1.x, b1.y, b1.z, b1.w};
#pragma unroll
      for (int i = 0; i < 8; ++i)
#pragma unroll
        for (int j = 0; j < 8; ++j) acc[i][j] += a[i] * bb[j];
    }
    __syncthreads();
  }
#pragma unroll
  for (int i = 0; i < 8; ++i) {
    int c = ty * 8 + i;
#pragma unroll
    for (int j = 0; j < 8; ++j) {
      int m = tx * 8 + j;
      sc[(size_t)bi * 16384 + c * 128 + m] = (m <= c) ? acc[i][j] : 0.f;
    }
  }
}

// ---------------------------------------------------------------------------
// out[c,e] = sum_d qs[c,d]*cum[d,e] + sum_m sc[c,m]*v[m,e]. One block per (b,h,n).
// ---------------------------------------------------------------------------
__global__ __launch_bounds__(256) void attn_out(const float* __restrict__ q,
                                                const float* __restrict__ cum,
                                                const float* __restrict__ sc,
                                                const float* __restrict__ v,
                                                float* __restrict__ attn) {
  int bi = blockIdx.x;
  int n = bi & 15, h = (bi >> 4) & 15, b = bi >> 8;
  int kvh = h >> 1;
  int rowbase = b * SEQ + n * CHUNK;
  size_t cumbase = (size_t)((b * 8 + kvh) * 16 + n) * 16384;
  size_t scbase = (size_t)bi * 16384;
  __shared__ float As[16][132], Bs[16][132];
  int tid = threadIdx.x, tx = tid & 15, ty = tid >> 4;
  float acc[8][8];
#pragma unroll
  for (int i = 0; i < 8; ++i)
#pragma unroll
    for (int j = 0; j < 8; ++j) acc[i][j] = 0.f;

  for (int ph = 0; ph < 2; ++ph) {
    for (int k0 = 0; k0 < 128; k0 += 16) {
#pragma unroll
      for (int i = 0; i < 2; ++i) {
        int lin = tid + i * 256;
        int r = lin >> 2, kq = lin & 3;  // A-operand (transposed into LDS)
        float4 va;
        if (ph == 0)
          va = *(const float4*)&q[(size_t)(rowbase + r) * DIMV + h * HD + k0 + kq * 4];
        else
          va = *(const float4*)&sc[scbase + (size_t)r * 128 + k0 + kq * 4];
        As[kq * 4 + 0][r] = va.x; As[kq * 4 + 1][r] = va.y;
        As[kq * 4 + 2][r] = va.z; As[kq * 4 + 3][r] = va.w;
        int kk2 = lin >> 5, eq = lin & 31;  // B-operand (direct)
        float4 vb;
        if (ph == 0)
          vb = *(const float4*)&cum[cumbase + (size_t)(k0 + kk2) * 128 + eq * 4];
        else
          vb = *(const float4*)&v[(size_t)(rowbase + k0 + kk2) * (NKV * HD) + kvh * HD + eq * 4];
        *(float4*)&Bs[kk2][eq * 4] = vb;
      }
      __syncthreads();
#pragma unroll
      for (int kk = 0; kk < 16; ++kk) {
        float4 a0 = *(const float4*)&As[kk][ty * 8];
        float4 a1 = *(const float4*)&As[kk][ty * 8 + 4];
        float4 b0 = *(const float4*)&Bs[kk][tx * 8];
        float4 b1 = *(const float4*)&Bs[kk][tx * 8 + 4];
        float a[8] = {a0.x, a0.y, a0.z, a0.w, a1.x, a1.y, a1.z, a1.w};
        float bb[8] = {b0.x, b0.y, b0.z, b0.w, b1.x, b1.y, b1.z, b1.w};
#pragma unroll
        for (int i = 0; i < 8; ++i)
#pragma unroll
          for (int j = 0; j < 8; ++j) acc[i][j] += a[i] * bb[j];
      }
      __syncthreads();
    }
  }
#pragma unroll
  for (int i = 0; i < 8; ++i) {
    int c = ty * 8 + i;
#pragma unroll
    for (int jq = 0; jq < 2; ++jq) {
      float4 vv = make_float4(acc[i][jq * 4], acc[i][jq * 4 + 1],
                              acc[i][jq * 4 + 2], acc[i][jq * 4 + 3]);
      *(float4*)&attn[(size_t)(rowbase + c) * DIMV + h * HD + tx * 8 + jq * 4] = vv;
    }
  }
}

// ---------------------------------------------------------------------------
extern "C" void kernel_launch(void* const* d_in, const int* in_sizes, int n_in,
                              void* d_out, int out_size, void* d_ws, size_t ws_size,
                              hipStream_t stream) {
  const float* x  = (const float*)d_in[0];
  const float* fc = (const float*)d_in[1];
  const float* wq = (const float*)d_in[2];
  const float* wk = (const float*)d_in[3];
  const float* wv = (const float*)d_in[4];
  const float* wo = (const float*)d_in[5];
  float* out = (float*)d_out;

  float* ws  = (float*)d_ws;
  float* qb  = ws;               // 4096*2048
  float* kb  = qb + 8388608;     // 4096*1024
  float* vb  = kb + 4194304;     // 4096*1024
  float* kvc = vb + 4194304;     // 2*8*16*128*128
  float* scb = kvc + 4194304;    // 2*16*16*128*128
  float* at  = scb + 8388608;    // 4096*2048

  // Projections
  gemm_bt<<<dim3(16, 32), 256, 0, stream>>>(x, wq, qb, MTOK, 2048, 2048);
  gemm_bt<<<dim3(8, 32), 256, 0, stream>>>(x, wk, kb, MTOK, 1024, 2048);
  gemm_bt<<<dim3(8, 32), 256, 0, stream>>>(x, wv, vb, MTOK, 1024, 2048);

  // RoPE + softmaxes
  rope_q_softmax<<<MTOK * NHEAD, 64, 0, stream>>>(qb, fc);
  rope_k<<<MTOK * NKV, 64, 0, stream>>>(kb, fc);
  kcol_softmax<<<BATCH * 1024, 256, 0, stream>>>(kb);

  // Chunked linear attention
  kv_chunk<<<BATCH * NKV * NCHUNK, 256, 0, stream>>>(kb, vb, kvc);
  cumsum_excl<<<1024, 256, 0, stream>>>(kvc);
  scores_nt<<<BATCH * NHEAD * NCHUNK, 256, 0, stream>>>(qb, kb, scb);
  attn_out<<<BATCH * NHEAD * NCHUNK, 256, 0, stream>>>(qb, kvc, scb, vb, at);

  // Output projection
  gemm_bt<<<dim3(16, 32), 256, 0, stream>>>(at, wo, out, MTOK, 2048, 2048);
}

// Round 2
// 589.927 us; speedup vs baseline: 2.8114x; 2.8114x over previous
//
#include <hip/hip_runtime.h>
#include <math.h>

#define DIMV 2048
#define NHEAD 16
#define NKV 8
#define HD 128
#define BATCH 2
#define SEQ 2048
#define CHUNK 128
#define NCHUNK 16
#define MTOK 4096  // BATCH*SEQ

typedef _Float16 half8_t __attribute__((ext_vector_type(8)));
typedef _Float16 half4_t __attribute__((ext_vector_type(4)));
typedef float f32x4 __attribute__((ext_vector_type(4)));

#define GLOBAL_AS __attribute__((address_space(1)))
#define LDS_AS __attribute__((address_space(3)))

// ---------------------------------------------------------------------------
// f32 -> f16 cast, 8 elems/thread. n multiple of 8.
// ---------------------------------------------------------------------------
__global__ __launch_bounds__(256) void cast_f2h(const float* __restrict__ in,
                                                _Float16* __restrict__ out, int n) {
  int i = (blockIdx.x * 256 + threadIdx.x) * 8;
  if (i >= n) return;
  float4 a = *(const float4*)&in[i];
  float4 b = *(const float4*)&in[i + 4];
  half8_t h = {(_Float16)a.x, (_Float16)a.y, (_Float16)a.z, (_Float16)a.w,
               (_Float16)b.x, (_Float16)b.y, (_Float16)b.z, (_Float16)b.w};
  *(half8_t*)&out[i] = h;
}

// ---------------------------------------------------------------------------
// MFMA fp16 GEMM: C[M,N] (f32) = A[M,K] @ B[N,K]^T, A/B fp16 row-major.
// 128x128 tile, BK=32, 256 threads = 4 waves, each wave 4x4 subtiles of
// 16x16x32. Staging via global_load_lds width=16 (m97 ladder structure).
// M,N multiples of 128; K multiple of 32.
// ---------------------------------------------------------------------------
__global__ __launch_bounds__(256) void hgemm_bt(const _Float16* __restrict__ A,
                                                const _Float16* __restrict__ B,
                                                float* __restrict__ C,
                                                int M, int N, int K) {
  __shared__ _Float16 As[128 * 32];
  __shared__ _Float16 Bs[128 * 32];
  const int tid = threadIdx.x;
  const int lane = tid & 63;
  const int wave = tid >> 6;
  const int row0 = blockIdx.y * 128, col0 = blockIdx.x * 128;
  const int wr = wave & 1, wc = wave >> 1;  // wave covers 64x64 at (wr*64, wc*64)
  const int m16 = lane & 15, quad = lane >> 4;

  f32x4 acc[4][4];
#pragma unroll
  for (int i = 0; i < 4; ++i)
#pragma unroll
    for (int j = 0; j < 4; ++j) acc[i][j] = (f32x4){0.f, 0.f, 0.f, 0.f};

  const int r_ld = tid >> 2;          // 0..63 row within half-tile
  const int seg = tid & 3;            // 8-half segment
  const size_t a_base = (size_t)(row0 + r_ld) * K + seg * 8;
  const size_t b_base = (size_t)(col0 + r_ld) * K + seg * 8;
  _Float16* ldsA = As + wave * 512;   // wave-uniform base, bytes = wave*1024
  _Float16* ldsB = Bs + wave * 512;

  for (int k0 = 0; k0 < K; k0 += 32) {
#pragma unroll
    for (int i = 0; i < 2; ++i) {
      __builtin_amdgcn_global_load_lds(
          (const GLOBAL_AS void*)(A + a_base + (size_t)i * 64 * K + k0),
          (LDS_AS void*)(ldsA + i * 2048), 16, 0, 0);
      __builtin_amdgcn_global_load_lds(
          (const GLOBAL_AS void*)(B + b_base + (size_t)i * 64 * K + k0),
          (LDS_AS void*)(ldsB + i * 2048), 16, 0, 0);
    }
    __syncthreads();

    half8_t af[4], bf[4];
#pragma unroll
    for (int i = 0; i < 4; ++i) {
      int m = wr * 64 + i * 16 + m16;
      af[i] = *(half8_t*)&As[m * 32 + quad * 8];
      int n = wc * 64 + i * 16 + m16;
      bf[i] = *(half8_t*)&Bs[n * 32 + quad * 8];
    }
#pragma unroll
    for (int i = 0; i < 4; ++i)
#pragma unroll
      for (int j = 0; j < 4; ++j)
        acc[i][j] = __builtin_amdgcn_mfma_f32_16x16x32_f16(af[i], bf[j], acc[i][j], 0, 0, 0);
    __syncthreads();
  }

  // Epilogue: C/D layout col=lane&15, row=quad*4+reg
#pragma unroll
  for (int i = 0; i < 4; ++i)
#pragma unroll
    for (int j = 0; j < 4; ++j) {
      int col = col0 + wc * 64 + j * 16 + m16;
#pragma unroll
      for (int r = 0; r < 4; ++r) {
        int row = row0 + wr * 64 + i * 16 + quad * 4 + r;
        C[(size_t)row * N + col] = acc[i][j][r];
      }
    }
}

// ---------------------------------------------------------------------------
// RoPE + row softmax (scale D^-0.5) on q. One wave per (token, head).
// ---------------------------------------------------------------------------
__global__ __launch_bounds__(64) void rope_q_softmax(float* __restrict__ q,
                                                     const float* __restrict__ fc) {
  int bi = blockIdx.x;
  int h = bi & (NHEAD - 1), m = bi >> 4;
  int s = m & (SEQ - 1);
  int t = threadIdx.x;
  size_t base = (size_t)m * DIMV + h * HD + 2 * t;
  float2 xv = *(const float2*)&q[base];
  float2 cs = *(const float2*)&fc[s * HD + 2 * t];
  float o0 = xv.x * cs.x - xv.y * cs.y;
  float o1 = xv.x * cs.y + xv.y * cs.x;
  const float sc = 0.08838834764831845f;  // 128^-0.5
  o0 *= sc; o1 *= sc;
  float mx = fmaxf(o0, o1);
#pragma unroll
  for (int off = 1; off < 64; off <<= 1) mx = fmaxf(mx, __shfl_xor(mx, off));
  float e0 = expf(o0 - mx), e1 = expf(o1 - mx);
  float sm = e0 + e1;
#pragma unroll
  for (int off = 1; off < 64; off <<= 1) sm += __shfl_xor(sm, off);
  float inv = 1.f / sm;
  *(float2*)&q[base] = make_float2(e0 * inv, e1 * inv);
}

// RoPE only on k.
__global__ __launch_bounds__(64) void rope_k(float* __restrict__ k,
                                             const float* __restrict__ fc) {
  int bi = blockIdx.x;
  int h = bi & (NKV - 1), m = bi >> 3;
  int s = m & (SEQ - 1);
  int t = threadIdx.x;
  size_t base = (size_t)m * (NKV * HD) + h * HD + 2 * t;
  float2 xv = *(const float2*)&k[base];
  float2 cs = *(const float2*)&fc[s * HD + 2 * t];
  *(float2*)&k[base] = make_float2(xv.x * cs.x - xv.y * cs.y,
                                   xv.x * cs.y + xv.y * cs.x);
}

// ---------------------------------------------------------------------------
// Column softmax over SEQ per (batch, col).
// ---------------------------------------------------------------------------
__global__ __launch_bounds__(256) void kcol_softmax(float* __restrict__ k) {
  int b = blockIdx.x >> 10, col = blockIdx.x & 1023;
  int tid = threadIdx.x;
  __shared__ float red[4];
  float vals[8];
  float mx = -1e30f;
#pragma unroll
  for (int i = 0; i < 8; ++i) {
    int s = tid + i * 256;
    vals[i] = k[(size_t)(b * SEQ + s) * (NKV * HD) + col];
    mx = fmaxf(mx, vals[i]);
  }
#pragma unroll
  for (int off = 1; off < 64; off <<= 1) mx = fmaxf(mx, __shfl_xor(mx, off));
  if ((tid & 63) == 0) red[tid >> 6] = mx;
  __syncthreads();
  if (tid == 0) red[0] = fmaxf(fmaxf(red[0], red[1]), fmaxf(red[2], red[3]));
  __syncthreads();
  mx = red[0];
  float sm = 0.f;
#pragma unroll
  for (int i = 0; i < 8; ++i) { vals[i] = expf(vals[i] - mx); sm += vals[i]; }
#pragma unroll
  for (int off = 1; off < 64; off <<= 1) sm += __shfl_xor(sm, off);
  __syncthreads();
  if ((tid & 63) == 0) red[tid >> 6] = sm;
  __syncthreads();
  if (tid == 0) red[0] = red[0] + red[1] + red[2] + red[3];
  __syncthreads();
  float inv = 1.f / red[0];
#pragma unroll
  for (int i = 0; i < 8; ++i) {
    int s = tid + i * 256;
    k[(size_t)(b * SEQ + s) * (NKV * HD) + col] = vals[i] * inv;
  }
}

// ---------------------------------------------------------------------------
// Per-chunk kv[d,e] = sum_c ks[c,d]*v[c,e].  One block per (b,kvh,n).
// ---------------------------------------------------------------------------
__global__ __launch_bounds__(256) void kv_chunk(const float* __restrict__ k,
                                                const float* __restrict__ v,
                                                float* __restrict__ kvc) {
  int bi = blockIdx.x;
  int n = bi & 15, kvh = (bi >> 4) & 7, b = bi >> 7;
  int rowbase = b * SEQ + n * CHUNK;
  int colbase = kvh * HD;
  __shared__ float Ks[16][132], Vs[16][132];
  int tid = threadIdx.x, tx = tid & 15, ty = tid >> 4;
  float acc[8][8];
#pragma unroll
  for (int i = 0; i < 8; ++i)
#pragma unroll
    for (int j = 0; j < 8; ++j) acc[i][j] = 0.f;

  for (int c0 = 0; c0 < CHUNK; c0 += 16) {
#pragma unroll
    for (int i = 0; i < 2; ++i) {
      int lin = tid + i * 256;
      int cc = lin >> 5, cq = lin & 31;
      size_t g = (size_t)(rowbase + c0 + cc) * (NKV * HD) + colbase + cq * 4;
      *(float4*)&Ks[cc][cq * 4] = *(const float4*)&k[g];
      *(float4*)&Vs[cc][cq * 4] = *(const float4*)&v[g];
    }
    __syncthreads();
#pragma unroll
    for (int cc = 0; cc < 16; ++cc) {
      float4 a0 = *(const float4*)&Ks[cc][ty * 8];
      float4 a1 = *(const float4*)&Ks[cc][ty * 8 + 4];
      float4 b0 = *(const float4*)&Vs[cc][tx * 8];
      float4 b1 = *(const float4*)&Vs[cc][tx * 8 + 4];
      float a[8] = {a0.x, a0.y, a0.z, a0.w, a1.x, a1.y, a1.z, a1.w};
      float bb[8] = {b0.x, b0.y, b0.z, b0.w, b1.x, b1.y, b1.z, b1.w};
#pragma unroll
      for (int i = 0; i < 8; ++i)
#pragma unroll
        for (int j = 0; j < 8; ++j) acc[i][j] += a[i] * bb[j];
    }
    __syncthreads();
  }
#pragma unroll
  for (int i = 0; i < 8; ++i) {
    int d = ty * 8 + i;
#pragma unroll
    for (int jq = 0; jq < 2; ++jq) {
      float4 vv = make_float4(acc[i][jq * 4], acc[i][jq * 4 + 1],
                              acc[i][jq * 4 + 2], acc[i][jq * 4 + 3]);
      *(float4*)&kvc[(size_t)bi * 16384 + d * 128 + tx * 8 + jq * 4] = vv;
    }
  }
}

// Exclusive cumsum over the 16 chunks, in place.
__global__ __launch_bounds__(256) void cumsum_excl(float* __restrict__ kvc) {
  int gid = blockIdx.x * 256 + threadIdx.x;
  int bk = gid >> 14;
  int idx = gid & 16383;
  size_t base = (size_t)bk * NCHUNK * 16384 + idx;
  float run = 0.f;
#pragma unroll
  for (int n = 0; n < NCHUNK; ++n) {
    float t = kvc[base + (size_t)n * 16384];
    kvc[base + (size_t)n * 16384] = run;
    run += t;
  }
}

// ---------------------------------------------------------------------------
// scores[c,m] = tril( sum_d qs[c,d]*ks[m,d] ).  One block per (b,h,n).
// ---------------------------------------------------------------------------
__global__ __launch_bounds__(256) void scores_nt(const float* __restrict__ q,
                                                 const float* __restrict__ k,
                                                 float* __restrict__ sc) {
  int bi = blockIdx.x;
  int n = bi & 15, h = (bi >> 4) & 15, b = bi >> 8;
  int kvh = h >> 1;
  int rowbase = b * SEQ + n * CHUNK;
  __shared__ float As[16][132], Bs[16][132];
  int tid = threadIdx.x, tx = tid & 15, ty = tid >> 4;
  float acc[8][8];
#pragma unroll
  for (int i = 0; i < 8; ++i)
#pragma unroll
    for (int j = 0; j < 8; ++j) acc[i][j] = 0.f;

  for (int k0 = 0; k0 < HD; k0 += 16) {
#pragma unroll
    for (int i = 0; i < 2; ++i) {
      int lin = tid + i * 256;
      int r = lin >> 2, kq = lin & 3;
      float4 va = *(const float4*)&q[(size_t)(rowbase + r) * DIMV + h * HD + k0 + kq * 4];
      As[kq * 4 + 0][r] = va.x; As[kq * 4 + 1][r] = va.y;
      As[kq * 4 + 2][r] = va.z; As[kq * 4 + 3][r] = va.w;
      float4 vb = *(const float4*)&k[(size_t)(rowbase + r) * (NKV * HD) + kvh * HD + k0 + kq * 4];
      Bs[kq * 4 + 0][r] = vb.x; Bs[kq * 4 + 1][r] = vb.y;
      Bs[kq * 4 + 2][r] = vb.z; Bs[kq * 4 + 3][r] = vb.w;
    }
    __syncthreads();
#pragma unroll
    for (int kk = 0; kk < 16; ++kk) {
      float4 a0 = *(const float4*)&As[kk][ty * 8];
      float4 a1 = *(const float4*)&As[kk][ty * 8 + 4];
      float4 b0 = *(const float4*)&Bs[kk][tx * 8];
      float4 b1 = *(const float4*)&Bs[kk][tx * 8 + 4];
      float a[8] = {a0.x, a0.y, a0.z, a0.w, a1.x, a1.y, a1.z, a1.w};
      float bb[8] = {b0.x, b0.y, b0.z, b0.w, b1.x, b1.y, b1.z, b1.w};
#pragma unroll
      for (int i = 0; i < 8; ++i)
#pragma unroll
        for (int j = 0; j < 8; ++j) acc[i][j] += a[i] * bb[j];
    }
    __syncthreads();
  }
#pragma unroll
  for (int i = 0; i < 8; ++i) {
    int c = ty * 8 + i;
#pragma unroll
    for (int j = 0; j < 8; ++j) {
      int m = tx * 8 + j;
      sc[(size_t)bi * 16384 + c * 128 + m] = (m <= c) ? acc[i][j] : 0.f;
    }
  }
}

// ---------------------------------------------------------------------------
// out[c,e] = q@cum + sc@v, written as fp16. One block per (b,h,n).
// ---------------------------------------------------------------------------
__global__ __launch_bounds__(256) void attn_out(const float* __restrict__ q,
                                                const float* __restrict__ cum,
                                                const float* __restrict__ sc,
                                                const float* __restrict__ v,
                                                _Float16* __restrict__ ath) {
  int bi = blockIdx.x;
  int n = bi & 15, h = (bi >> 4) & 15, b = bi >> 8;
  int kvh = h >> 1;
  int rowbase = b * SEQ + n * CHUNK;
  size_t cumbase = (size_t)((b * 8 + kvh) * 16 + n) * 16384;
  size_t scbase = (size_t)bi * 16384;
  __shared__ float As[16][132], Bs[16][132];
  int tid = threadIdx.x, tx = tid & 15, ty = tid >> 4;
  float acc[8][8];
#pragma unroll
  for (int i = 0; i < 8; ++i)
#pragma unroll
    for (int j = 0; j < 8; ++j) acc[i][j] = 0.f;

  for (int ph = 0; ph < 2; ++ph) {
    for (int k0 = 0; k0 < 128; k0 += 16) {
#pragma unroll
      for (int i = 0; i < 2; ++i) {
        int lin = tid + i * 256;
        int r = lin >> 2, kq = lin & 3;
        float4 va;
        if (ph == 0)
          va = *(const float4*)&q[(size_t)(rowbase + r) * DIMV + h * HD + k0 + kq * 4];
        else
          va = *(const float4*)&sc[scbase + (size_t)r * 128 + k0 + kq * 4];
        As[kq * 4 + 0][r] = va.x; As[kq * 4 + 1][r] = va.y;
        As[kq * 4 + 2][r] = va.z; As[kq * 4 + 3][r] = va.w;
        int kk2 = lin >> 5, eq = lin & 31;
        float4 vb;
        if (ph == 0)
          vb = *(const float4*)&cum[cumbase + (size_t)(k0 + kk2) * 128 + eq * 4];
        else
          vb = *(const float4*)&v[(size_t)(rowbase + k0 + kk2) * (NKV * HD) + kvh * HD + eq * 4];
        *(float4*)&Bs[kk2][eq * 4] = vb;
      }
      __syncthreads();
#pragma unroll
      for (int kk = 0; kk < 16; ++kk) {
        float4 a0 = *(const float4*)&As[kk][ty * 8];
        float4 a1 = *(const float4*)&As[kk][ty * 8 + 4];
        float4 b0 = *(const float4*)&Bs[kk][tx * 8];
        float4 b1 = *(const float4*)&Bs[kk][tx * 8 + 4];
        float a[8] = {a0.x, a0.y, a0.z, a0.w, a1.x, a1.y, a1.z, a1.w};
        float bb[8] = {b0.x, b0.y, b0.z, b0.w, b1.x, b1.y, b1.z, b1.w};
#pragma unroll
        for (int i = 0; i < 8; ++i)
#pragma unroll
          for (int j = 0; j < 8; ++j) acc[i][j] += a[i] * bb[j];
      }
      __syncthreads();
    }
  }
#pragma unroll
  for (int i = 0; i < 8; ++i) {
    int c = ty * 8 + i;
#pragma unroll
    for (int jq = 0; jq < 2; ++jq) {
      half4_t hv = {(_Float16)acc[i][jq * 4 + 0], (_Float16)acc[i][jq * 4 + 1],
                    (_Float16)acc[i][jq * 4 + 2], (_Float16)acc[i][jq * 4 + 3]};
      *(half4_t*)&ath[(size_t)(rowbase + c) * DIMV + h * HD + tx * 8 + jq * 4] = hv;
    }
  }
}

// ---------------------------------------------------------------------------
extern "C" void kernel_launch(void* const* d_in, const int* in_sizes, int n_in,
                              void* d_out, int out_size, void* d_ws, size_t ws_size,
                              hipStream_t stream) {
  const float* x  = (const float*)d_in[0];
  const float* fc = (const float*)d_in[1];
  const float* wq = (const float*)d_in[2];
  const float* wk = (const float*)d_in[3];
  const float* wv = (const float*)d_in[4];
  const float* wo = (const float*)d_in[5];
  float* out = (float*)d_out;

  float* ws  = (float*)d_ws;
  float* qb  = ws;               // 4096*2048 f32
  float* kb  = qb + 8388608;     // 4096*1024 f32
  float* vb  = kb + 4194304;     // 4096*1024 f32
  float* kvc = vb + 4194304;     // 2*8*16*128*128 f32
  float* scb = kvc + 4194304;    // 2*16*16*128*128 f32
  _Float16* xh  = (_Float16*)(scb + 8388608);  // 4096*2048 f16
  _Float16* wqh = xh + 8388608;                // 2048*2048 f16
  _Float16* wkh = wqh + 4194304;               // 1024*2048 f16
  _Float16* wvh = wkh + 2097152;               // 1024*2048 f16
  _Float16* woh = wvh + 2097152;               // 2048*2048 f16
  _Float16* ath = woh + 4194304;               // 4096*2048 f16

  // Casts to fp16
  cast_f2h<<<4096, 256, 0, stream>>>(x, xh, 8388608);
  cast_f2h<<<2048, 256, 0, stream>>>(wq, wqh, 4194304);
  cast_f2h<<<1024, 256, 0, stream>>>(wk, wkh, 2097152);
  cast_f2h<<<1024, 256, 0, stream>>>(wv, wvh, 2097152);
  cast_f2h<<<2048, 256, 0, stream>>>(wo, woh, 4194304);

  // Projections (MFMA fp16)
  hgemm_bt<<<dim3(16, 32), 256, 0, stream>>>(xh, wqh, qb, MTOK, 2048, 2048);
  hgemm_bt<<<dim3(8, 32), 256, 0, stream>>>(xh, wkh, kb, MTOK, 1024, 2048);
  hgemm_bt<<<dim3(8, 32), 256, 0, stream>>>(xh, wvh, vb, MTOK, 1024, 2048);

  // RoPE + softmaxes (f32)
  rope_q_softmax<<<MTOK * NHEAD, 64, 0, stream>>>(qb, fc);
  rope_k<<<MTOK * NKV, 64, 0, stream>>>(kb, fc);
  kcol_softmax<<<BATCH * 1024, 256, 0, stream>>>(kb);

  // Chunked linear attention (f32)
  kv_chunk<<<BATCH * NKV * NCHUNK, 256, 0, stream>>>(kb, vb, kvc);
  cumsum_excl<<<1024, 256, 0, stream>>>(kvc);
  scores_nt<<<BATCH * NHEAD * NCHUNK, 256, 0, stream>>>(qb, kb, scb);
  attn_out<<<BATCH * NHEAD * NCHUNK, 256, 0, stream>>>(qb, kvc, scb, vb, ath);

  // Output projection (MFMA fp16)
  hgemm_bt<<<dim3(16, 32), 256, 0, stream>>>(ath, woh, out, MTOK, 2048, 2048);
}

// Round 3
// 399.498 us; speedup vs baseline: 4.1514x; 1.4767x over previous
//
#include <hip/hip_runtime.h>
#include <math.h>

#define DIMV 2048
#define NHEAD 16
#define NKV 8
#define HD 128
#define BATCH 2
#define SEQ 2048
#define CHUNK 128
#define NCHUNK 16
#define MTOK 4096  // BATCH*SEQ
#define KVD (NKV * HD)  // 1024

typedef _Float16 half8_t __attribute__((ext_vector_type(8)));
typedef _Float16 half4_t __attribute__((ext_vector_type(4)));
typedef _Float16 half2_t __attribute__((ext_vector_type(2)));
typedef float f32x4 __attribute__((ext_vector_type(4)));

#define GLOBAL_AS __attribute__((address_space(1)))
#define LDS_AS __attribute__((address_space(3)))

// ---------------------------------------------------------------------------
// f32 -> f16 cast, 8 elems/thread.
// ---------------------------------------------------------------------------
__global__ __launch_bounds__(256) void cast_f2h(const float* __restrict__ in,
                                                _Float16* __restrict__ out, int n) {
  int i = (blockIdx.x * 256 + threadIdx.x) * 8;
  if (i >= n) return;
  float4 a = *(const float4*)&in[i];
  float4 b = *(const float4*)&in[i + 4];
  half8_t h = {(_Float16)a.x, (_Float16)a.y, (_Float16)a.z, (_Float16)a.w,
               (_Float16)b.x, (_Float16)b.y, (_Float16)b.z, (_Float16)b.w};
  *(half8_t*)&out[i] = h;
}

// ---------------------------------------------------------------------------
// fc [2048][128] -> fcT [128][2048]   (f32, LDS tile transpose)
// grid (32, 2), 256 threads.
// ---------------------------------------------------------------------------
__global__ __launch_bounds__(256) void transpose_fc(const float* __restrict__ fc,
                                                    float* __restrict__ fcT) {
  __shared__ float T[64][65];
  int s0 = blockIdx.x * 64, d0 = blockIdx.y * 64;
  int t = threadIdx.x;
  int r = t >> 4, c4 = (t & 15) * 4;
#pragma unroll
  for (int p = 0; p < 4; ++p) {
    int sr = p * 16 + r;
    float4 v = *(const float4*)&fc[(size_t)(s0 + sr) * 128 + d0 + c4];
    T[sr][c4] = v.x; T[sr][c4 + 1] = v.y; T[sr][c4 + 2] = v.z; T[sr][c4 + 3] = v.w;
  }
  __syncthreads();
#pragma unroll
  for (int p = 0; p < 4; ++p) {
    int dr = p * 16 + r;
    float4 v = make_float4(T[c4][dr], T[c4 + 1][dr], T[c4 + 2][dr], T[c4 + 3][dr]);
    *(float4*)&fcT[(size_t)(d0 + dr) * SEQ + s0 + c4] = v;
  }
}

// ---------------------------------------------------------------------------
// MFMA fp16 GEMM: A[M,K] @ B[N,K]^T, fp16 row-major inputs.
// OM=0: C f32 [M][N]; OM=1: C f16 [M][N]; OM=2: C f16 transposed [N][M].
// 128x128 tile, BK=32, 4 waves x (4x4) 16x16x32 frags, global_load_lds w=16.
// ---------------------------------------------------------------------------
template <int OM>
__global__ __launch_bounds__(256) void hgemm_bt(const _Float16* __restrict__ A,
                                                const _Float16* __restrict__ B,
                                                void* __restrict__ Cv,
                                                int M, int N, int K) {
  __shared__ _Float16 As[128 * 32];
  __shared__ _Float16 Bs[128 * 32];
  const int tid = threadIdx.x;
  const int lane = tid & 63;
  const int wave = tid >> 6;
  const int row0 = blockIdx.y * 128, col0 = blockIdx.x * 128;
  const int wr = wave & 1, wc = wave >> 1;
  const int m16 = lane & 15, quad = lane >> 4;

  f32x4 acc[4][4];
#pragma unroll
  for (int i = 0; i < 4; ++i)
#pragma unroll
    for (int j = 0; j < 4; ++j) acc[i][j] = (f32x4){0.f, 0.f, 0.f, 0.f};

  const int r_ld = tid >> 2;
  const int seg = tid & 3;
  const size_t a_base = (size_t)(row0 + r_ld) * K + seg * 8;
  const size_t b_base = (size_t)(col0 + r_ld) * K + seg * 8;
  _Float16* ldsA = As + wave * 512;
  _Float16* ldsB = Bs + wave * 512;

  for (int k0 = 0; k0 < K; k0 += 32) {
#pragma unroll
    for (int i = 0; i < 2; ++i) {
      __builtin_amdgcn_global_load_lds(
          (const GLOBAL_AS void*)(A + a_base + (size_t)i * 64 * K + k0),
          (LDS_AS void*)(ldsA + i * 2048), 16, 0, 0);
      __builtin_amdgcn_global_load_lds(
          (const GLOBAL_AS void*)(B + b_base + (size_t)i * 64 * K + k0),
          (LDS_AS void*)(ldsB + i * 2048), 16, 0, 0);
    }
    __syncthreads();

    half8_t af[4], bf[4];
#pragma unroll
    for (int i = 0; i < 4; ++i) {
      int m = wr * 64 + i * 16 + m16;
      af[i] = *(half8_t*)&As[m * 32 + quad * 8];
      int n = wc * 64 + i * 16 + m16;
      bf[i] = *(half8_t*)&Bs[n * 32 + quad * 8];
    }
#pragma unroll
    for (int i = 0; i < 4; ++i)
#pragma unroll
      for (int j = 0; j < 4; ++j)
        acc[i][j] = __builtin_amdgcn_mfma_f32_16x16x32_f16(af[i], bf[j], acc[i][j], 0, 0, 0);
    __syncthreads();
  }

#pragma unroll
  for (int i = 0; i < 4; ++i)
#pragma unroll
    for (int j = 0; j < 4; ++j) {
      int col = col0 + wc * 64 + j * 16 + m16;
      int rowb = row0 + wr * 64 + i * 16 + quad * 4;
      if (OM == 0) {
        float* C = (float*)Cv;
#pragma unroll
        for (int r = 0; r < 4; ++r) C[(size_t)(rowb + r) * N + col] = acc[i][j][r];
      } else if (OM == 1) {
        _Float16* C = (_Float16*)Cv;
#pragma unroll
        for (int r = 0; r < 4; ++r) C[(size_t)(rowb + r) * N + col] = (_Float16)acc[i][j][r];
      } else {
        _Float16* Ct = (_Float16*)Cv;
        half4_t hv = {(_Float16)acc[i][j][0], (_Float16)acc[i][j][1],
                      (_Float16)acc[i][j][2], (_Float16)acc[i][j][3]};
        *(half4_t*)&Ct[(size_t)col * M + rowb] = hv;
      }
    }
}

// ---------------------------------------------------------------------------
// RoPE + row softmax on q, fp16 in/out (f32 internally). Wave per (token,head).
// ---------------------------------------------------------------------------
__global__ __launch_bounds__(64) void rope_q_softmax_h(_Float16* __restrict__ q,
                                                       const float* __restrict__ fc) {
  int bi = blockIdx.x;
  int h = bi & (NHEAD - 1), m = bi >> 4;
  int s = m & (SEQ - 1);
  int t = threadIdx.x;
  size_t base = (size_t)m * DIMV + h * HD + 2 * t;
  half2_t xv = *(const half2_t*)&q[base];
  float2 cs = *(const float2*)&fc[s * HD + 2 * t];
  float x0 = (float)xv[0], x1 = (float)xv[1];
  float o0 = x0 * cs.x - x1 * cs.y;
  float o1 = x0 * cs.y + x1 * cs.x;
  const float sc = 0.08838834764831845f;  // 128^-0.5
  o0 *= sc; o1 *= sc;
  float mx = fmaxf(o0, o1);
#pragma unroll
  for (int off = 1; off < 64; off <<= 1) mx = fmaxf(mx, __shfl_xor(mx, off));
  float e0 = expf(o0 - mx), e1 = expf(o1 - mx);
  float sm = e0 + e1;
#pragma unroll
  for (int off = 1; off < 64; off <<= 1) sm += __shfl_xor(sm, off);
  float inv = 1.f / sm;
  half2_t ov = {(_Float16)(e0 * inv), (_Float16)(e1 * inv)};
  *(half2_t*)&q[base] = ov;
}

// ---------------------------------------------------------------------------
// RoPE + token-softmax on kT [1024 dims][4096 tokens] fp16, in place.
// Block per (rope pair, batch): grid 1024, 256 threads x 8 tokens.
// No max subtraction (|k|<~5, f32 exp safe; mathematically identical).
// ---------------------------------------------------------------------------
__global__ __launch_bounds__(256) void k_rope_softmax_T(_Float16* __restrict__ kT,
                                                        const float* __restrict__ fcT) {
  int bi = blockIdx.x;
  int b = bi & 1, pr = bi >> 1;     // pr 0..511
  int d0 = pr * 2, dl = d0 & 127;   // local even dim within head
  int t = threadIdx.x;
  size_t r0 = (size_t)d0 * MTOK + b * SEQ + t * 8;
  size_t r1 = r0 + MTOK;
  half8_t x0v = *(half8_t*)&kT[r0];
  half8_t x1v = *(half8_t*)&kT[r1];
  int s8 = t * 8;
  float4 ca = *(const float4*)&fcT[(size_t)dl * SEQ + s8];
  float4 cb = *(const float4*)&fcT[(size_t)dl * SEQ + s8 + 4];
  float4 sa = *(const float4*)&fcT[(size_t)(dl + 1) * SEQ + s8];
  float4 sb = *(const float4*)&fcT[(size_t)(dl + 1) * SEQ + s8 + 4];
  float cc[8] = {ca.x, ca.y, ca.z, ca.w, cb.x, cb.y, cb.z, cb.w};
  float ss[8] = {sa.x, sa.y, sa.z, sa.w, sb.x, sb.y, sb.z, sb.w};
  float e0[8], e1[8];
  float sum0 = 0.f, sum1 = 0.f;
#pragma unroll
  for (int j = 0; j < 8; ++j) {
    float x0 = (float)x0v[j], x1 = (float)x1v[j];
    float o0 = x0 * cc[j] - x1 * ss[j];
    float o1 = x0 * ss[j] + x1 * cc[j];
    e0[j] = expf(o0); e1[j] = expf(o1);
    sum0 += e0[j]; sum1 += e1[j];
  }
#pragma unroll
  for (int off = 1; off < 64; off <<= 1) {
    sum0 += __shfl_xor(sum0, off);
    sum1 += __shfl_xor(sum1, off);
  }
  __shared__ float red[8];
  if ((t & 63) == 0) { red[(t >> 6) * 2] = sum0; red[(t >> 6) * 2 + 1] = sum1; }
  __syncthreads();
  float S0 = red[0] + red[2] + red[4] + red[6];
  float S1 = red[1] + red[3] + red[5] + red[7];
  float i0 = 1.f / S0, i1 = 1.f / S1;
  half8_t w0, w1;
#pragma unroll
  for (int j = 0; j < 8; ++j) {
    w0[j] = (_Float16)(e0[j] * i0);
    w1[j] = (_Float16)(e1[j] * i1);
  }
  *(half8_t*)&kT[r0] = w0;
  *(half8_t*)&kT[r1] = w1;
}

// ---------------------------------------------------------------------------
// kT [1024][4096] -> kh [4096][1024]  (fp16 tile transpose)
// grid (64, 16), 256 threads, 64x64 tiles.
// ---------------------------------------------------------------------------
__global__ __launch_bounds__(256) void transpose_k(const _Float16* __restrict__ kT,
                                                   _Float16* __restrict__ kh) {
  __shared__ _Float16 T[64][65];  // T[token][dim]
  int t0 = blockIdx.x * 64, d0 = blockIdx.y * 64;
  int t = threadIdx.x;
  int r = t >> 3, c8 = (t & 7) * 8;
#pragma unroll
  for (int p = 0; p < 2; ++p) {
    int dr = p * 32 + r;
    half8_t v = *(const half8_t*)&kT[(size_t)(d0 + dr) * MTOK + t0 + c8];
#pragma unroll
    for (int j = 0; j < 8; ++j) T[c8 + j][dr] = v[j];
  }
  __syncthreads();
#pragma unroll
  for (int p = 0; p < 2; ++p) {
    int tr = p * 32 + r;
    half8_t v;
#pragma unroll
    for (int j = 0; j < 8; ++j) v[j] = T[tr][c8 + j];
    *(half8_t*)&kh[(size_t)(t0 + tr) * KVD + d0 + c8] = v;
  }
}

// ---------------------------------------------------------------------------
// kvT[e][d] = sum_c v[c,e]*k[c,d] per (b,kvh,chunk). MFMA fp16, M=N=K=128.
// A = vT rows (e over tokens), B = kT rows (d over tokens). 256 blocks.
// ---------------------------------------------------------------------------
__global__ __launch_bounds__(256) void kv_chunk_mfma(const _Float16* __restrict__ vT,
                                                     const _Float16* __restrict__ kT,
                                                     float* __restrict__ kvT) {
  __shared__ _Float16 As[128 * 32];
  __shared__ _Float16 Bs[128 * 32];
  int bi = blockIdx.x;
  int n = bi & 15, kvh = (bi >> 4) & 7, b = bi >> 7;
  int tok0 = b * SEQ + n * CHUNK;
  const int tid = threadIdx.x;
  const int lane = tid & 63;
  const int wave = tid >> 6;
  const int wr = wave & 1, wc = wave >> 1;
  const int m16 = lane & 15, quad = lane >> 4;

  f32x4 acc[4][4];
#pragma unroll
  for (int i = 0; i < 4; ++i)
#pragma unroll
    for (int j = 0; j < 4; ++j) acc[i][j] = (f32x4){0.f, 0.f, 0.f, 0.f};

  const int r_ld = tid >> 2;
  const int seg = tid & 3;
  const size_t a_base = (size_t)(kvh * HD + r_ld) * MTOK + tok0 + seg * 8;
  const size_t b_base = a_base;  // kT has same geometry (head-dim rows x tokens)
  _Float16* ldsA = As + wave * 512;
  _Float16* ldsB = Bs + wave * 512;

  for (int k0 = 0; k0 < 128; k0 += 32) {
#pragma unroll
    for (int i = 0; i < 2; ++i) {
      __builtin_amdgcn_global_load_lds(
          (const GLOBAL_AS void*)(vT + a_base + (size_t)i * 64 * MTOK + k0),
          (LDS_AS void*)(ldsA + i * 2048), 16, 0, 0);
      __builtin_amdgcn_global_load_lds(
          (const GLOBAL_AS void*)(kT + b_base + (size_t)i * 64 * MTOK + k0),
          (LDS_AS void*)(ldsB + i * 2048), 16, 0, 0);
    }
    __syncthreads();
    half8_t af[4], bf[4];
#pragma unroll
    for (int i = 0; i < 4; ++i) {
      af[i] = *(half8_t*)&As[(wr * 64 + i * 16 + m16) * 32 + quad * 8];
      bf[i] = *(half8_t*)&Bs[(wc * 64 + i * 16 + m16) * 32 + quad * 8];
    }
#pragma unroll
    for (int i = 0; i < 4; ++i)
#pragma unroll
      for (int j = 0; j < 4; ++j)
        acc[i][j] = __builtin_amdgcn_mfma_f32_16x16x32_f16(af[i], bf[j], acc[i][j], 0, 0, 0);
    __syncthreads();
  }
#pragma unroll
  for (int i = 0; i < 4; ++i)
#pragma unroll
    for (int j = 0; j < 4; ++j) {
      int col = wc * 64 + j * 16 + m16;
      int rowb = wr * 64 + i * 16 + quad * 4;
#pragma unroll
      for (int r = 0; r < 4; ++r)
        kvT[(size_t)bi * 16384 + (size_t)(rowb + r) * 128 + col] = acc[i][j][r];
    }
}

// ---------------------------------------------------------------------------
// Exclusive chunk-cumsum of kvT (f32), emitting fp16 cumT. grid 1024x256.
// ---------------------------------------------------------------------------
__global__ __launch_bounds__(256) void cumsum_h(const float* __restrict__ kvT,
                                                _Float16* __restrict__ cumh) {
  int gid = blockIdx.x * 256 + threadIdx.x;
  int bk = gid >> 14, idx = gid & 16383;
  size_t base = (size_t)bk * NCHUNK * 16384 + idx;
  float run = 0.f;
#pragma unroll
  for (int n = 0; n < NCHUNK; ++n) {
    cumh[base + (size_t)n * 16384] = (_Float16)run;
    run += kvT[base + (size_t)n * 16384];
  }
}

// ---------------------------------------------------------------------------
// Fused scores+output per (b,h,chunk): S = tril(q@k^T) -> LDS fp16;
// out = q@cumT + S@v, all fp16 MFMA, f32 accum. 512 blocks, 256 threads.
// ---------------------------------------------------------------------------
__global__ __launch_bounds__(256) void attn_fused(const _Float16* __restrict__ qh,
                                                  const _Float16* __restrict__ kh,
                                                  const _Float16* __restrict__ cumh,
                                                  const _Float16* __restrict__ vT,
                                                  _Float16* __restrict__ ath) {
  __shared__ _Float16 As[128 * 32];
  __shared__ _Float16 Bs[128 * 32];
  __shared__ _Float16 Ss[128][136];  // S in [c][m'] layout, 16B-aligned rows
  int bi = blockIdx.x;
  int n = bi & 15, h = (bi >> 4) & 15, b = bi >> 8;
  int kvh = h >> 1;
  int tok0 = b * SEQ + n * CHUNK;
  const int tid = threadIdx.x;
  const int lane = tid & 63;
  const int wave = tid >> 6;
  const int wr = wave & 1, wc = wave >> 1;
  const int m16 = lane & 15, quad = lane >> 4;
  const int r_ld = tid >> 2;
  const int seg = tid & 3;
  _Float16* ldsA = As + wave * 512;
  _Float16* ldsB = Bs + wave * 512;

  f32x4 acc[4][4];
#pragma unroll
  for (int i = 0; i < 4; ++i)
#pragma unroll
    for (int j = 0; j < 4; ++j) acc[i][j] = (f32x4){0.f, 0.f, 0.f, 0.f};

  const size_t qbase = (size_t)(tok0 + r_ld) * DIMV + h * HD + seg * 8;
  const size_t kbase = (size_t)(tok0 + r_ld) * KVD + kvh * HD + seg * 8;
  const size_t cbase = ((size_t)((b * 8 + kvh) * 16 + n)) * 16384 + (size_t)r_ld * 128 + seg * 8;
  const size_t vbase = (size_t)(kvh * HD + r_ld) * MTOK + tok0 + seg * 8;

  // ---- Phase A: S = q @ k^T over d ----
  for (int k0 = 0; k0 < 128; k0 += 32) {
#pragma unroll
    for (int i = 0; i < 2; ++i) {
      __builtin_amdgcn_global_load_lds(
          (const GLOBAL_AS void*)(qh + qbase + (size_t)i * 64 * DIMV + k0),
          (LDS_AS void*)(ldsA + i * 2048), 16, 0, 0);
      __builtin_amdgcn_global_load_lds(
          (const GLOBAL_AS void*)(kh + kbase + (size_t)i * 64 * KVD + k0),
          (LDS_AS void*)(ldsB + i * 2048), 16, 0, 0);
    }
    __syncthreads();
    half8_t af[4], bf[4];
#pragma unroll
    for (int i = 0; i < 4; ++i) {
      af[i] = *(half8_t*)&As[(wr * 64 + i * 16 + m16) * 32 + quad * 8];
      bf[i] = *(half8_t*)&Bs[(wc * 64 + i * 16 + m16) * 32 + quad * 8];
    }
#pragma unroll
    for (int i = 0; i < 4; ++i)
#pragma unroll
      for (int j = 0; j < 4; ++j)
        acc[i][j] = __builtin_amdgcn_mfma_f32_16x16x32_f16(af[i], bf[j], acc[i][j], 0, 0, 0);
    __syncthreads();
  }

  // masked store of S to LDS, then reset accumulators
#pragma unroll
  for (int i = 0; i < 4; ++i)
#pragma unroll
    for (int j = 0; j < 4; ++j) {
      int col = wc * 64 + j * 16 + m16;
      int rowb = wr * 64 + i * 16 + quad * 4;
#pragma unroll
      for (int r = 0; r < 4; ++r) {
        float v = (col <= rowb + r) ? acc[i][j][r] : 0.f;
        Ss[rowb + r][col] = (_Float16)v;
      }
      acc[i][j] = (f32x4){0.f, 0.f, 0.f, 0.f};
    }

  // ---- Phase B1 (inter): out += q @ cumT ----
  for (int ks = 0; ks < 4; ++ks) {
    int k0 = ks * 32;
#pragma unroll
    for (int i = 0; i < 2; ++i) {
      __builtin_amdgcn_global_load_lds(
          (const GLOBAL_AS void*)(qh + qbase + (size_t)i * 64 * DIMV + k0),
          (LDS_AS void*)(ldsA + i * 2048), 16, 0, 0);
      __builtin_amdgcn_global_load_lds(
          (const GLOBAL_AS void*)(cumh + cbase + (size_t)i * 64 * 128 + k0),
          (LDS_AS void*)(ldsB + i * 2048), 16, 0, 0);
    }
    __syncthreads();
    half8_t af[4], bf[4];
#pragma unroll
    for (int i = 0; i < 4; ++i) {
      af[i] = *(half8_t*)&As[(wr * 64 + i * 16 + m16) * 32 + quad * 8];
      bf[i] = *(half8_t*)&Bs[(wc * 64 + i * 16 + m16) * 32 + quad * 8];
    }
#pragma unroll
    for (int i = 0; i < 4; ++i)
#pragma unroll
      for (int j = 0; j < 4; ++j)
        acc[i][j] = __builtin_amdgcn_mfma_f32_16x16x32_f16(af[i], bf[j], acc[i][j], 0, 0, 0);
    __syncthreads();
  }

  // ---- Phase B2 (intra): out += S @ v (A from Ss, B = vT rows) ----
  for (int ks = 0; ks < 4; ++ks) {
    int k0 = ks * 32;
#pragma unroll
    for (int i = 0; i < 2; ++i) {
      __builtin_amdgcn_global_load_lds(
          (const GLOBAL_AS void*)(vT + vbase + (size_t)i * 64 * MTOK + k0),
          (LDS_AS void*)(ldsB + i * 2048), 16, 0, 0);
    }
    __syncthreads();
    half8_t af[4], bf[4];
#pragma unroll
    for (int i = 0; i < 4; ++i) {
      af[i] = *(half8_t*)&Ss[wr * 64 + i * 16 + m16][k0 + quad * 8];
      bf[i] = *(half8_t*)&Bs[(wc * 64 + i * 16 + m16) * 32 + quad * 8];
    }
#pragma unroll
    for (int i = 0; i < 4; ++i)
#pragma unroll
      for (int j = 0; j < 4; ++j)
        acc[i][j] = __builtin_amdgcn_mfma_f32_16x16x32_f16(af[i], bf[j], acc[i][j], 0, 0, 0);
    __syncthreads();
  }

  // epilogue: fp16 token-major output
#pragma unroll
  for (int i = 0; i < 4; ++i)
#pragma unroll
    for (int j = 0; j < 4; ++j) {
      int col = wc * 64 + j * 16 + m16;
      int rowb = wr * 64 + i * 16 + quad * 4;
#pragma unroll
      for (int r = 0; r < 4; ++r)
        ath[(size_t)(tok0 + rowb + r) * DIMV + h * HD + col] = (_Float16)acc[i][j][r];
    }
}

// ---------------------------------------------------------------------------
extern "C" void kernel_launch(void* const* d_in, const int* in_sizes, int n_in,
                              void* d_out, int out_size, void* d_ws, size_t ws_size,
                              hipStream_t stream) {
  const float* x  = (const float*)d_in[0];
  const float* fc = (const float*)d_in[1];
  const float* wq = (const float*)d_in[2];
  const float* wk = (const float*)d_in[3];
  const float* wv = (const float*)d_in[4];
  const float* wo = (const float*)d_in[5];
  float* out = (float*)d_out;

  char* p = (char*)d_ws;
  _Float16* xh  = (_Float16*)p;            p += 16777216;  // 4096x2048
  _Float16* wqh = (_Float16*)p;            p += 8388608;   // 2048x2048
  _Float16* wkh = (_Float16*)p;            p += 4194304;   // 1024x2048
  _Float16* wvh = (_Float16*)p;            p += 4194304;   // 1024x2048
  _Float16* woh = (_Float16*)p;            p += 8388608;   // 2048x2048
  _Float16* qh  = (_Float16*)p;            p += 16777216;  // 4096x2048
  _Float16* kT  = (_Float16*)p;            p += 8388608;   // 1024x4096
  _Float16* kh  = (_Float16*)p;            p += 8388608;   // 4096x1024
  _Float16* vT  = (_Float16*)p;            p += 8388608;   // 1024x4096
  float*    kvT = (float*)p;               p += 16777216;  // 256x128x128 f32
  _Float16* cumh= (_Float16*)p;            p += 8388608;
  _Float16* ath = (_Float16*)p;            p += 16777216;  // 4096x2048
  float*    fcT = (float*)p;               p += 1048576;   // 128x2048 f32

  // casts
  cast_f2h<<<4096, 256, 0, stream>>>(x, xh, 8388608);
  cast_f2h<<<2048, 256, 0, stream>>>(wq, wqh, 4194304);
  cast_f2h<<<1024, 256, 0, stream>>>(wk, wkh, 2097152);
  cast_f2h<<<1024, 256, 0, stream>>>(wv, wvh, 2097152);
  cast_f2h<<<2048, 256, 0, stream>>>(wo, woh, 4194304);
  transpose_fc<<<dim3(32, 2), 256, 0, stream>>>(fc, fcT);

  // projections
  hgemm_bt<1><<<dim3(16, 32), 256, 0, stream>>>(xh, wqh, qh, MTOK, 2048, 2048);
  hgemm_bt<2><<<dim3(8, 32), 256, 0, stream>>>(xh, wkh, kT, MTOK, 1024, 2048);
  hgemm_bt<2><<<dim3(8, 32), 256, 0, stream>>>(xh, wvh, vT, MTOK, 1024, 2048);

  // rope + softmaxes
  rope_q_softmax_h<<<MTOK * NHEAD, 64, 0, stream>>>(qh, fc);
  k_rope_softmax_T<<<1024, 256, 0, stream>>>(kT, fcT);
  transpose_k<<<dim3(64, 16), 256, 0, stream>>>(kT, kh);

  // chunked linear attention (fp16 MFMA)
  kv_chunk_mfma<<<256, 256, 0, stream>>>(vT, kT, kvT);
  cumsum_h<<<1024, 256, 0, stream>>>(kvT, cumh);
  attn_fused<<<512, 256, 0, stream>>>(qh, kh, cumh, vT, ath);

  // output projection
  hgemm_bt<0><<<dim3(16, 32), 256, 0, stream>>>(ath, woh, out, MTOK, 2048, 2048);
}

// Round 4
// 337.079 us; speedup vs baseline: 4.9202x; 1.1852x over previous
//
#include <hip/hip_runtime.h>
#include <math.h>

#define DIMV 2048
#define NHEAD 16
#define NKV 8
#define HD 128
#define BATCH 2
#define SEQ 2048
#define CHUNK 128
#define NCHUNK 16
#define MTOK 4096  // BATCH*SEQ
#define KVD (NKV * HD)  // 1024

typedef _Float16 half8_t __attribute__((ext_vector_type(8)));
typedef _Float16 half4_t __attribute__((ext_vector_type(4)));
typedef _Float16 half2_t __attribute__((ext_vector_type(2)));
typedef float f32x4 __attribute__((ext_vector_type(4)));

#define GLOBAL_AS __attribute__((address_space(1)))
#define LDS_AS __attribute__((address_space(3)))

// ---------------------------------------------------------------------------
// f32 -> f16 cast, 8 elems/thread.
// ---------------------------------------------------------------------------
__global__ __launch_bounds__(256) void cast_f2h(const float* __restrict__ in,
                                                _Float16* __restrict__ out, int n) {
  int i = (blockIdx.x * 256 + threadIdx.x) * 8;
  if (i >= n) return;
  float4 a = *(const float4*)&in[i];
  float4 b = *(const float4*)&in[i + 4];
  half8_t h = {(_Float16)a.x, (_Float16)a.y, (_Float16)a.z, (_Float16)a.w,
               (_Float16)b.x, (_Float16)b.y, (_Float16)b.z, (_Float16)b.w};
  *(half8_t*)&out[i] = h;
}

// ---------------------------------------------------------------------------
// fc [2048][128] -> fcT [128][2048]   (f32, LDS tile transpose)
// ---------------------------------------------------------------------------
__global__ __launch_bounds__(256) void transpose_fc(const float* __restrict__ fc,
                                                    float* __restrict__ fcT) {
  __shared__ float T[64][65];
  int s0 = blockIdx.x * 64, d0 = blockIdx.y * 64;
  int t = threadIdx.x;
  int r = t >> 4, c4 = (t & 15) * 4;
#pragma unroll
  for (int p = 0; p < 4; ++p) {
    int sr = p * 16 + r;
    float4 v = *(const float4*)&fc[(size_t)(s0 + sr) * 128 + d0 + c4];
    T[sr][c4] = v.x; T[sr][c4 + 1] = v.y; T[sr][c4 + 2] = v.z; T[sr][c4 + 3] = v.w;
  }
  __syncthreads();
#pragma unroll
  for (int p = 0; p < 4; ++p) {
    int dr = p * 16 + r;
    float4 v = make_float4(T[c4][dr], T[c4 + 1][dr], T[c4 + 2][dr], T[c4 + 3][dr]);
    *(float4*)&fcT[(size_t)(d0 + dr) * SEQ + s0 + c4] = v;
  }
}

// ===========================================================================
// BK=64 MFMA fp16 GEMM core macros.
// Tile 128x128, 256 threads = 4 waves, each wave 4x4 of 16x16x32 frags.
// LDS 2 x 16 KB; staging: 4 issues of global_load_lds width=16 per operand.
// Loader: thread covers row r_ld=tid>>3 (+32/issue), seg=tid&7 (8 halves).
// ===========================================================================

// ---------------------------------------------------------------------------
// Fused QKV projection: C[M=4096][N=4096] = xh @ wqkv^T, epilogue splits:
//   col <  2048        -> qh[tok][col]        (f16 row-major)
//   2048 <= col < 3072 -> kT[col-2048][tok]   (f16 transposed)
//   3072 <= col        -> vT[col-3072][tok]   (f16 transposed)
// grid dim3(32, 32).
// ---------------------------------------------------------------------------
__global__ __launch_bounds__(256) void hgemm_qkv(const _Float16* __restrict__ A,
                                                 const _Float16* __restrict__ B,
                                                 _Float16* __restrict__ qh,
                                                 _Float16* __restrict__ kT,
                                                 _Float16* __restrict__ vT) {
  const int K = 2048;
  __shared__ _Float16 As[128 * 64];
  __shared__ _Float16 Bs[128 * 64];
  const int tid = threadIdx.x;
  const int lane = tid & 63;
  const int wave = tid >> 6;
  const int row0 = blockIdx.y * 128, col0 = blockIdx.x * 128;
  const int wr = wave & 1, wc = wave >> 1;
  const int m16 = lane & 15, quad = lane >> 4;

  f32x4 acc[4][4];
#pragma unroll
  for (int i = 0; i < 4; ++i)
#pragma unroll
    for (int j = 0; j < 4; ++j) acc[i][j] = (f32x4){0.f, 0.f, 0.f, 0.f};

  const int r_ld = tid >> 3;     // 0..31
  const int seg = tid & 7;       // 8-half segment
  const size_t a_base = (size_t)(row0 + r_ld) * K + seg * 8;
  const size_t b_base = (size_t)(col0 + r_ld) * K + seg * 8;
  _Float16* ldsA = As + wave * 512;   // wave-uniform base + lane*16B
  _Float16* ldsB = Bs + wave * 512;

  for (int k0 = 0; k0 < K; k0 += 64) {
#pragma unroll
    for (int i = 0; i < 4; ++i) {
      __builtin_amdgcn_global_load_lds(
          (const GLOBAL_AS void*)(A + a_base + (size_t)i * 32 * K + k0),
          (LDS_AS void*)(ldsA + i * 2048), 16, 0, 0);
      __builtin_amdgcn_global_load_lds(
          (const GLOBAL_AS void*)(B + b_base + (size_t)i * 32 * K + k0),
          (LDS_AS void*)(ldsB + i * 2048), 16, 0, 0);
    }
    __syncthreads();
#pragma unroll
    for (int kk = 0; kk < 2; ++kk) {
      half8_t af[4], bf[4];
#pragma unroll
      for (int i = 0; i < 4; ++i) {
        af[i] = *(half8_t*)&As[(wr * 64 + i * 16 + m16) * 64 + kk * 32 + quad * 8];
        bf[i] = *(half8_t*)&Bs[(wc * 64 + i * 16 + m16) * 64 + kk * 32 + quad * 8];
      }
#pragma unroll
      for (int i = 0; i < 4; ++i)
#pragma unroll
        for (int j = 0; j < 4; ++j)
          acc[i][j] = __builtin_amdgcn_mfma_f32_16x16x32_f16(af[i], bf[j], acc[i][j], 0, 0, 0);
    }
    __syncthreads();
  }

#pragma unroll
  for (int i = 0; i < 4; ++i)
#pragma unroll
    for (int j = 0; j < 4; ++j) {
      int col = col0 + wc * 64 + j * 16 + m16;
      int rowb = row0 + wr * 64 + i * 16 + quad * 4;
      half4_t hv = {(_Float16)acc[i][j][0], (_Float16)acc[i][j][1],
                    (_Float16)acc[i][j][2], (_Float16)acc[i][j][3]};
      if (col0 < 2048) {
#pragma unroll
        for (int r = 0; r < 4; ++r) qh[(size_t)(rowb + r) * DIMV + col] = hv[r];
      } else if (col0 < 3072) {
        *(half4_t*)&kT[(size_t)(col - 2048) * MTOK + rowb] = hv;
      } else {
        *(half4_t*)&vT[(size_t)(col - 3072) * MTOK + rowb] = hv;
      }
    }
}

// ---------------------------------------------------------------------------
// BK=64 GEMM, f32 output row-major: C = A[M,K] @ B[N,K]^T. grid (N/128, M/128).
// ---------------------------------------------------------------------------
__global__ __launch_bounds__(256) void hgemm_bt64_f32(const _Float16* __restrict__ A,
                                                      const _Float16* __restrict__ B,
                                                      float* __restrict__ C,
                                                      int M, int N, int K) {
  __shared__ _Float16 As[128 * 64];
  __shared__ _Float16 Bs[128 * 64];
  const int tid = threadIdx.x;
  const int lane = tid & 63;
  const int wave = tid >> 6;
  const int row0 = blockIdx.y * 128, col0 = blockIdx.x * 128;
  const int wr = wave & 1, wc = wave >> 1;
  const int m16 = lane & 15, quad = lane >> 4;

  f32x4 acc[4][4];
#pragma unroll
  for (int i = 0; i < 4; ++i)
#pragma unroll
    for (int j = 0; j < 4; ++j) acc[i][j] = (f32x4){0.f, 0.f, 0.f, 0.f};

  const int r_ld = tid >> 3;
  const int seg = tid & 7;
  const size_t a_base = (size_t)(row0 + r_ld) * K + seg * 8;
  const size_t b_base = (size_t)(col0 + r_ld) * K + seg * 8;
  _Float16* ldsA = As + wave * 512;
  _Float16* ldsB = Bs + wave * 512;

  for (int k0 = 0; k0 < K; k0 += 64) {
#pragma unroll
    for (int i = 0; i < 4; ++i) {
      __builtin_amdgcn_global_load_lds(
          (const GLOBAL_AS void*)(A + a_base + (size_t)i * 32 * K + k0),
          (LDS_AS void*)(ldsA + i * 2048), 16, 0, 0);
      __builtin_amdgcn_global_load_lds(
          (const GLOBAL_AS void*)(B + b_base + (size_t)i * 32 * K + k0),
          (LDS_AS void*)(ldsB + i * 2048), 16, 0, 0);
    }
    __syncthreads();
#pragma unroll
    for (int kk = 0; kk < 2; ++kk) {
      half8_t af[4], bf[4];
#pragma unroll
      for (int i = 0; i < 4; ++i) {
        af[i] = *(half8_t*)&As[(wr * 64 + i * 16 + m16) * 64 + kk * 32 + quad * 8];
        bf[i] = *(half8_t*)&Bs[(wc * 64 + i * 16 + m16) * 64 + kk * 32 + quad * 8];
      }
#pragma unroll
      for (int i = 0; i < 4; ++i)
#pragma unroll
        for (int j = 0; j < 4; ++j)
          acc[i][j] = __builtin_amdgcn_mfma_f32_16x16x32_f16(af[i], bf[j], acc[i][j], 0, 0, 0);
    }
    __syncthreads();
  }

#pragma unroll
  for (int i = 0; i < 4; ++i)
#pragma unroll
    for (int j = 0; j < 4; ++j) {
      int col = col0 + wc * 64 + j * 16 + m16;
      int rowb = row0 + wr * 64 + i * 16 + quad * 4;
#pragma unroll
      for (int r = 0; r < 4; ++r) C[(size_t)(rowb + r) * N + col] = acc[i][j][r];
    }
}

// ---------------------------------------------------------------------------
// RoPE + row softmax on q, fp16 in/out (f32 internally). Wave per (token,head).
// ---------------------------------------------------------------------------
__global__ __launch_bounds__(64) void rope_q_softmax_h(_Float16* __restrict__ q,
                                                       const float* __restrict__ fc) {
  int bi = blockIdx.x;
  int h = bi & (NHEAD - 1), m = bi >> 4;
  int s = m & (SEQ - 1);
  int t = threadIdx.x;
  size_t base = (size_t)m * DIMV + h * HD + 2 * t;
  half2_t xv = *(const half2_t*)&q[base];
  float2 cs = *(const float2*)&fc[s * HD + 2 * t];
  float x0 = (float)xv[0], x1 = (float)xv[1];
  float o0 = x0 * cs.x - x1 * cs.y;
  float o1 = x0 * cs.y + x1 * cs.x;
  const float sc = 0.08838834764831845f;  // 128^-0.5
  o0 *= sc; o1 *= sc;
  float mx = fmaxf(o0, o1);
#pragma unroll
  for (int off = 1; off < 64; off <<= 1) mx = fmaxf(mx, __shfl_xor(mx, off));
  float e0 = expf(o0 - mx), e1 = expf(o1 - mx);
  float sm = e0 + e1;
#pragma unroll
  for (int off = 1; off < 64; off <<= 1) sm += __shfl_xor(sm, off);
  float inv = 1.f / sm;
  half2_t ov = {(_Float16)(e0 * inv), (_Float16)(e1 * inv)};
  *(half2_t*)&q[base] = ov;
}

// ---------------------------------------------------------------------------
// RoPE + token-softmax on kT [1024 dims][4096 tokens] fp16, in place.
// ---------------------------------------------------------------------------
__global__ __launch_bounds__(256) void k_rope_softmax_T(_Float16* __restrict__ kT,
                                                        const float* __restrict__ fcT) {
  int bi = blockIdx.x;
  int b = bi & 1, pr = bi >> 1;
  int d0 = pr * 2, dl = d0 & 127;
  int t = threadIdx.x;
  size_t r0 = (size_t)d0 * MTOK + b * SEQ + t * 8;
  size_t r1 = r0 + MTOK;
  half8_t x0v = *(half8_t*)&kT[r0];
  half8_t x1v = *(half8_t*)&kT[r1];
  int s8 = t * 8;
  float4 ca = *(const float4*)&fcT[(size_t)dl * SEQ + s8];
  float4 cb = *(const float4*)&fcT[(size_t)dl * SEQ + s8 + 4];
  float4 sa = *(const float4*)&fcT[(size_t)(dl + 1) * SEQ + s8];
  float4 sb = *(const float4*)&fcT[(size_t)(dl + 1) * SEQ + s8 + 4];
  float cc[8] = {ca.x, ca.y, ca.z, ca.w, cb.x, cb.y, cb.z, cb.w};
  float ss[8] = {sa.x, sa.y, sa.z, sa.w, sb.x, sb.y, sb.z, sb.w};
  float e0[8], e1[8];
  float sum0 = 0.f, sum1 = 0.f;
#pragma unroll
  for (int j = 0; j < 8; ++j) {
    float x0 = (float)x0v[j], x1 = (float)x1v[j];
    float o0 = x0 * cc[j] - x1 * ss[j];
    float o1 = x0 * ss[j] + x1 * cc[j];
    e0[j] = expf(o0); e1[j] = expf(o1);
    sum0 += e0[j]; sum1 += e1[j];
  }
#pragma unroll
  for (int off = 1; off < 64; off <<= 1) {
    sum0 += __shfl_xor(sum0, off);
    sum1 += __shfl_xor(sum1, off);
  }
  __shared__ float red[8];
  if ((t & 63) == 0) { red[(t >> 6) * 2] = sum0; red[(t >> 6) * 2 + 1] = sum1; }
  __syncthreads();
  float S0 = red[0] + red[2] + red[4] + red[6];
  float S1 = red[1] + red[3] + red[5] + red[7];
  float i0 = 1.f / S0, i1 = 1.f / S1;
  half8_t w0, w1;
#pragma unroll
  for (int j = 0; j < 8; ++j) {
    w0[j] = (_Float16)(e0[j] * i0);
    w1[j] = (_Float16)(e1[j] * i1);
  }
  *(half8_t*)&kT[r0] = w0;
  *(half8_t*)&kT[r1] = w1;
}

// ---------------------------------------------------------------------------
// kT [1024][4096] -> kh [4096][1024]  (fp16 tile transpose)
// ---------------------------------------------------------------------------
__global__ __launch_bounds__(256) void transpose_k(const _Float16* __restrict__ kT,
                                                   _Float16* __restrict__ kh) {
  __shared__ _Float16 T[64][65];
  int t0 = blockIdx.x * 64, d0 = blockIdx.y * 64;
  int t = threadIdx.x;
  int r = t >> 3, c8 = (t & 7) * 8;
#pragma unroll
  for (int p = 0; p < 2; ++p) {
    int dr = p * 32 + r;
    half8_t v = *(const half8_t*)&kT[(size_t)(d0 + dr) * MTOK + t0 + c8];
#pragma unroll
    for (int j = 0; j < 8; ++j) T[c8 + j][dr] = v[j];
  }
  __syncthreads();
#pragma unroll
  for (int p = 0; p < 2; ++p) {
    int tr = p * 32 + r;
    half8_t v;
#pragma unroll
    for (int j = 0; j < 8; ++j) v[j] = T[tr][c8 + j];
    *(half8_t*)&kh[(size_t)(t0 + tr) * KVD + d0 + c8] = v;
  }
}

// ---------------------------------------------------------------------------
// kvT[e][d] = sum_c v[c,e]*k[c,d] per (b,kvh,chunk). MFMA fp16, M=N=K=128.
// ---------------------------------------------------------------------------
__global__ __launch_bounds__(256) void kv_chunk_mfma(const _Float16* __restrict__ vT,
                                                     const _Float16* __restrict__ kT,
                                                     float* __restrict__ kvT) {
  __shared__ _Float16 As[128 * 32];
  __shared__ _Float16 Bs[128 * 32];
  int bi = blockIdx.x;
  int n = bi & 15, kvh = (bi >> 4) & 7, b = bi >> 7;
  int tok0 = b * SEQ + n * CHUNK;
  const int tid = threadIdx.x;
  const int lane = tid & 63;
  const int wave = tid >> 6;
  const int wr = wave & 1, wc = wave >> 1;
  const int m16 = lane & 15, quad = lane >> 4;

  f32x4 acc[4][4];
#pragma unroll
  for (int i = 0; i < 4; ++i)
#pragma unroll
    for (int j = 0; j < 4; ++j) acc[i][j] = (f32x4){0.f, 0.f, 0.f, 0.f};

  const int r_ld = tid >> 2;
  const int seg = tid & 3;
  const size_t a_base = (size_t)(kvh * HD + r_ld) * MTOK + tok0 + seg * 8;
  const size_t b_base = a_base;
  _Float16* ldsA = As + wave * 512;
  _Float16* ldsB = Bs + wave * 512;

  for (int k0 = 0; k0 < 128; k0 += 32) {
#pragma unroll
    for (int i = 0; i < 2; ++i) {
      __builtin_amdgcn_global_load_lds(
          (const GLOBAL_AS void*)(vT + a_base + (size_t)i * 64 * MTOK + k0),
          (LDS_AS void*)(ldsA + i * 2048), 16, 0, 0);
      __builtin_amdgcn_global_load_lds(
          (const GLOBAL_AS void*)(kT + b_base + (size_t)i * 64 * MTOK + k0),
          (LDS_AS void*)(ldsB + i * 2048), 16, 0, 0);
    }
    __syncthreads();
    half8_t af[4], bf[4];
#pragma unroll
    for (int i = 0; i < 4; ++i) {
      af[i] = *(half8_t*)&As[(wr * 64 + i * 16 + m16) * 32 + quad * 8];
      bf[i] = *(half8_t*)&Bs[(wc * 64 + i * 16 + m16) * 32 + quad * 8];
    }
#pragma unroll
    for (int i = 0; i < 4; ++i)
#pragma unroll
      for (int j = 0; j < 4; ++j)
        acc[i][j] = __builtin_amdgcn_mfma_f32_16x16x32_f16(af[i], bf[j], acc[i][j], 0, 0, 0);
    __syncthreads();
  }
#pragma unroll
  for (int i = 0; i < 4; ++i)
#pragma unroll
    for (int j = 0; j < 4; ++j) {
      int col = wc * 64 + j * 16 + m16;
      int rowb = wr * 64 + i * 16 + quad * 4;
#pragma unroll
      for (int r = 0; r < 4; ++r)
        kvT[(size_t)bi * 16384 + (size_t)(rowb + r) * 128 + col] = acc[i][j][r];
    }
}

// ---------------------------------------------------------------------------
// Exclusive chunk-cumsum of kvT (f32), emitting fp16 cumT. grid 1024x256.
// ---------------------------------------------------------------------------
__global__ __launch_bounds__(256) void cumsum_h(const float* __restrict__ kvT,
                                                _Float16* __restrict__ cumh) {
  int gid = blockIdx.x * 256 + threadIdx.x;
  int bk = gid >> 14, idx = gid & 16383;
  size_t base = (size_t)bk * NCHUNK * 16384 + idx;
  float run = 0.f;
#pragma unroll
  for (int n = 0; n < NCHUNK; ++n) {
    cumh[base + (size_t)n * 16384] = (_Float16)run;
    run += kvT[base + (size_t)n * 16384];
  }
}

// ---------------------------------------------------------------------------
// Fused scores+output per (b,h,chunk): S = tril(q@k^T) -> LDS fp16;
// out = q@cumT + S@v, all fp16 MFMA, f32 accum. 512 blocks, 256 threads.
// ---------------------------------------------------------------------------
__global__ __launch_bounds__(256) void attn_fused(const _Float16* __restrict__ qh,
                                                  const _Float16* __restrict__ kh,
                                                  const _Float16* __restrict__ cumh,
                                                  const _Float16* __restrict__ vT,
                                                  _Float16* __restrict__ ath) {
  __shared__ _Float16 As[128 * 32];
  __shared__ _Float16 Bs[128 * 32];
  __shared__ _Float16 Ss[128][136];
  int bi = blockIdx.x;
  int n = bi & 15, h = (bi >> 4) & 15, b = bi >> 8;
  int kvh = h >> 1;
  int tok0 = b * SEQ + n * CHUNK;
  const int tid = threadIdx.x;
  const int lane = tid & 63;
  const int wave = tid >> 6;
  const int wr = wave & 1, wc = wave >> 1;
  const int m16 = lane & 15, quad = lane >> 4;
  const int r_ld = tid >> 2;
  const int seg = tid & 3;
  _Float16* ldsA = As + wave * 512;
  _Float16* ldsB = Bs + wave * 512;

  f32x4 acc[4][4];
#pragma unroll
  for (int i = 0; i < 4; ++i)
#pragma unroll
    for (int j = 0; j < 4; ++j) acc[i][j] = (f32x4){0.f, 0.f, 0.f, 0.f};

  const size_t qbase = (size_t)(tok0 + r_ld) * DIMV + h * HD + seg * 8;
  const size_t kbase = (size_t)(tok0 + r_ld) * KVD + kvh * HD + seg * 8;
  const size_t cbase = ((size_t)((b * 8 + kvh) * 16 + n)) * 16384 + (size_t)r_ld * 128 + seg * 8;
  const size_t vbase = (size_t)(kvh * HD + r_ld) * MTOK + tok0 + seg * 8;

  // ---- Phase A: S = q @ k^T over d ----
  for (int k0 = 0; k0 < 128; k0 += 32) {
#pragma unroll
    for (int i = 0; i < 2; ++i) {
      __builtin_amdgcn_global_load_lds(
          (const GLOBAL_AS void*)(qh + qbase + (size_t)i * 64 * DIMV + k0),
          (LDS_AS void*)(ldsA + i * 2048), 16, 0, 0);
      __builtin_amdgcn_global_load_lds(
          (const GLOBAL_AS void*)(kh + kbase + (size_t)i * 64 * KVD + k0),
          (LDS_AS void*)(ldsB + i * 2048), 16, 0, 0);
    }
    __syncthreads();
    half8_t af[4], bf[4];
#pragma unroll
    for (int i = 0; i < 4; ++i) {
      af[i] = *(half8_t*)&As[(wr * 64 + i * 16 + m16) * 32 + quad * 8];
      bf[i] = *(half8_t*)&Bs[(wc * 64 + i * 16 + m16) * 32 + quad * 8];
    }
#pragma unroll
    for (int i = 0; i < 4; ++i)
#pragma unroll
      for (int j = 0; j < 4; ++j)
        acc[i][j] = __builtin_amdgcn_mfma_f32_16x16x32_f16(af[i], bf[j], acc[i][j], 0, 0, 0);
    __syncthreads();
  }

#pragma unroll
  for (int i = 0; i < 4; ++i)
#pragma unroll
    for (int j = 0; j < 4; ++j) {
      int col = wc * 64 + j * 16 + m16;
      int rowb = wr * 64 + i * 16 + quad * 4;
#pragma unroll
      for (int r = 0; r < 4; ++r) {
        float v = (col <= rowb + r) ? acc[i][j][r] : 0.f;
        Ss[rowb + r][col] = (_Float16)v;
      }
      acc[i][j] = (f32x4){0.f, 0.f, 0.f, 0.f};
    }

  // ---- Phase B1 (inter): out += q @ cumT ----
  for (int ks = 0; ks < 4; ++ks) {
    int k0 = ks * 32;
#pragma unroll
    for (int i = 0; i < 2; ++i) {
      __builtin_amdgcn_global_load_lds(
          (const GLOBAL_AS void*)(qh + qbase + (size_t)i * 64 * DIMV + k0),
          (LDS_AS void*)(ldsA + i * 2048), 16, 0, 0);
      __builtin_amdgcn_global_load_lds(
          (const GLOBAL_AS void*)(cumh + cbase + (size_t)i * 64 * 128 + k0),
          (LDS_AS void*)(ldsB + i * 2048), 16, 0, 0);
    }
    __syncthreads();
    half8_t af[4], bf[4];
#pragma unroll
    for (int i = 0; i < 4; ++i) {
      af[i] = *(half8_t*)&As[(wr * 64 + i * 16 + m16) * 32 + quad * 8];
      bf[i] = *(half8_t*)&Bs[(wc * 64 + i * 16 + m16) * 32 + quad * 8];
    }
#pragma unroll
    for (int i = 0; i < 4; ++i)
#pragma unroll
      for (int j = 0; j < 4; ++j)
        acc[i][j] = __builtin_amdgcn_mfma_f32_16x16x32_f16(af[i], bf[j], acc[i][j], 0, 0, 0);
    __syncthreads();
  }

  // ---- Phase B2 (intra): out += S @ v ----
  for (int ks = 0; ks < 4; ++ks) {
    int k0 = ks * 32;
#pragma unroll
    for (int i = 0; i < 2; ++i) {
      __builtin_amdgcn_global_load_lds(
          (const GLOBAL_AS void*)(vT + vbase + (size_t)i * 64 * MTOK + k0),
          (LDS_AS void*)(ldsB + i * 2048), 16, 0, 0);
    }
    __syncthreads();
    half8_t af[4], bf[4];
#pragma unroll
    for (int i = 0; i < 4; ++i) {
      af[i] = *(half8_t*)&Ss[wr * 64 + i * 16 + m16][k0 + quad * 8];
      bf[i] = *(half8_t*)&Bs[(wc * 64 + i * 16 + m16) * 32 + quad * 8];
    }
#pragma unroll
    for (int i = 0; i < 4; ++i)
#pragma unroll
      for (int j = 0; j < 4; ++j)
        acc[i][j] = __builtin_amdgcn_mfma_f32_16x16x32_f16(af[i], bf[j], acc[i][j], 0, 0, 0);
    __syncthreads();
  }

#pragma unroll
  for (int i = 0; i < 4; ++i)
#pragma unroll
    for (int j = 0; j < 4; ++j) {
      int col = wc * 64 + j * 16 + m16;
      int rowb = wr * 64 + i * 16 + quad * 4;
#pragma unroll
      for (int r = 0; r < 4; ++r)
        ath[(size_t)(tok0 + rowb + r) * DIMV + h * HD + col] = (_Float16)acc[i][j][r];
    }
}

// ---------------------------------------------------------------------------
extern "C" void kernel_launch(void* const* d_in, const int* in_sizes, int n_in,
                              void* d_out, int out_size, void* d_ws, size_t ws_size,
                              hipStream_t stream) {
  const float* x  = (const float*)d_in[0];
  const float* fc = (const float*)d_in[1];
  const float* wq = (const float*)d_in[2];
  const float* wk = (const float*)d_in[3];
  const float* wv = (const float*)d_in[4];
  const float* wo = (const float*)d_in[5];
  float* out = (float*)d_out;

  char* p = (char*)d_ws;
  _Float16* xh    = (_Float16*)p;  p += 16777216;  // 4096x2048
  _Float16* wqkvh = (_Float16*)p;  p += 16777216;  // 4096x2048 (wq|wk|wv)
  _Float16* woh   = (_Float16*)p;  p += 8388608;   // 2048x2048
  _Float16* qh    = (_Float16*)p;  p += 16777216;  // 4096x2048
  _Float16* kT    = (_Float16*)p;  p += 8388608;   // 1024x4096
  _Float16* kh    = (_Float16*)p;  p += 8388608;   // 4096x1024
  _Float16* vT    = (_Float16*)p;  p += 8388608;   // 1024x4096
  float*    kvT   = (float*)p;     p += 16777216;  // 256x128x128 f32
  _Float16* cumh  = (_Float16*)p;  p += 8388608;
  _Float16* ath   = (_Float16*)p;  p += 16777216;  // 4096x2048
  float*    fcT   = (float*)p;     p += 1048576;   // 128x2048 f32

  // casts (wq|wk|wv concatenated into one [4096][2048] fp16 weight)
  cast_f2h<<<4096, 256, 0, stream>>>(x, xh, 8388608);
  cast_f2h<<<2048, 256, 0, stream>>>(wq, wqkvh, 4194304);
  cast_f2h<<<1024, 256, 0, stream>>>(wk, wqkvh + 4194304, 2097152);
  cast_f2h<<<1024, 256, 0, stream>>>(wv, wqkvh + 6291456, 2097152);
  cast_f2h<<<2048, 256, 0, stream>>>(wo, woh, 4194304);
  transpose_fc<<<dim3(32, 2), 256, 0, stream>>>(fc, fcT);

  // fused QKV projection (1024 blocks)
  hgemm_qkv<<<dim3(32, 32), 256, 0, stream>>>(xh, wqkvh, qh, kT, vT);

  // rope + softmaxes
  rope_q_softmax_h<<<MTOK * NHEAD, 64, 0, stream>>>(qh, fc);
  k_rope_softmax_T<<<1024, 256, 0, stream>>>(kT, fcT);
  transpose_k<<<dim3(64, 16), 256, 0, stream>>>(kT, kh);

  // chunked linear attention (fp16 MFMA)
  kv_chunk_mfma<<<256, 256, 0, stream>>>(vT, kT, kvT);
  cumsum_h<<<1024, 256, 0, stream>>>(kvT, cumh);
  attn_fused<<<512, 256, 0, stream>>>(qh, kh, cumh, vT, ath);

  // output projection
  hgemm_bt64_f32<<<dim3(16, 32), 256, 0, stream>>>(ath, woh, out, MTOK, 2048, 2048);
}

// Round 5
// 315.836 us; speedup vs baseline: 5.2511x; 1.0673x over previous
//
#include <hip/hip_runtime.h>
#include <math.h>

#define DIMV 2048
#define NHEAD 16
#define NKV 8
#define HD 128
#define BATCH 2
#define SEQ 2048
#define CHUNK 128
#define NCHUNK 16
#define MTOK 4096  // BATCH*SEQ
#define KVD (NKV * HD)  // 1024

typedef _Float16 half8_t __attribute__((ext_vector_type(8)));
typedef _Float16 half4_t __attribute__((ext_vector_type(4)));
typedef _Float16 half2_t __attribute__((ext_vector_type(2)));
typedef float f32x4 __attribute__((ext_vector_type(4)));

#define GLOBAL_AS __attribute__((address_space(1)))
#define LDS_AS __attribute__((address_space(3)))

// ---------------------------------------------------------------------------
// f32 -> f16 cast, 8 elems/thread.
// ---------------------------------------------------------------------------
__global__ __launch_bounds__(256) void cast_f2h(const float* __restrict__ in,
                                                _Float16* __restrict__ out, int n) {
  int i = (blockIdx.x * 256 + threadIdx.x) * 8;
  if (i >= n) return;
  float4 a = *(const float4*)&in[i];
  float4 b = *(const float4*)&in[i + 4];
  half8_t h = {(_Float16)a.x, (_Float16)a.y, (_Float16)a.z, (_Float16)a.w,
               (_Float16)b.x, (_Float16)b.y, (_Float16)b.z, (_Float16)b.w};
  *(half8_t*)&out[i] = h;
}

// ---------------------------------------------------------------------------
// fc [2048][128] -> fcT [128][2048]   (f32, LDS tile transpose)
// ---------------------------------------------------------------------------
__global__ __launch_bounds__(256) void transpose_fc(const float* __restrict__ fc,
                                                    float* __restrict__ fcT) {
  __shared__ float T[64][65];
  int s0 = blockIdx.x * 64, d0 = blockIdx.y * 64;
  int t = threadIdx.x;
  int r = t >> 4, c4 = (t & 15) * 4;
#pragma unroll
  for (int p = 0; p < 4; ++p) {
    int sr = p * 16 + r;
    float4 v = *(const float4*)&fc[(size_t)(s0 + sr) * 128 + d0 + c4];
    T[sr][c4] = v.x; T[sr][c4 + 1] = v.y; T[sr][c4 + 2] = v.z; T[sr][c4 + 3] = v.w;
  }
  __syncthreads();
#pragma unroll
  for (int p = 0; p < 4; ++p) {
    int dr = p * 16 + r;
    float4 v = make_float4(T[c4][dr], T[c4 + 1][dr], T[c4 + 2][dr], T[c4 + 3][dr]);
    *(float4*)&fcT[(size_t)(d0 + dr) * SEQ + s0 + c4] = v;
  }
}

// ===========================================================================
// BK=64 swizzled MFMA fp16 GEMM core.
// Tile 128x128, 256 threads = 4 waves, each wave 4x4 of 16x16x32 frags.
// LDS layout: logical segment c (8 halves) of row r stored at c^(r&7) —
// spreads ds_read_b128 bank quads across all 32 banks (conflict-free),
// while keeping global_load_lds's lane-contiguous destination contract.
// ===========================================================================

// ---------------------------------------------------------------------------
// Fused QKV projection: C[4096][4096] = xh @ wqkv^T, epilogue splits:
//   col <  2048        -> qh[tok][col]        (f16 row-major)
//   2048 <= col < 3072 -> kT[col-2048][tok]   (f16 transposed)
//   3072 <= col        -> vT[col-3072][tok]   (f16 transposed)
// grid dim3(32, 32).
// ---------------------------------------------------------------------------
__global__ __launch_bounds__(256) void hgemm_qkv(const _Float16* __restrict__ A,
                                                 const _Float16* __restrict__ B,
                                                 _Float16* __restrict__ qh,
                                                 _Float16* __restrict__ kT,
                                                 _Float16* __restrict__ vT) {
  const int K = 2048;
  __shared__ _Float16 As[128 * 64];
  __shared__ _Float16 Bs[128 * 64];
  const int tid = threadIdx.x;
  const int lane = tid & 63;
  const int wave = tid >> 6;
  const int row0 = blockIdx.y * 128, col0 = blockIdx.x * 128;
  const int wr = wave & 1, wc = wave >> 1;
  const int m16 = lane & 15, quad = lane >> 4;

  f32x4 acc[4][4];
#pragma unroll
  for (int i = 0; i < 4; ++i)
#pragma unroll
    for (int j = 0; j < 4; ++j) acc[i][j] = (f32x4){0.f, 0.f, 0.f, 0.f};

  const int r_ld = tid >> 3;                 // 0..31
  const int sseg = (tid & 7) ^ (r_ld & 7);   // swizzled source segment
  const size_t a_base = (size_t)(row0 + r_ld) * K + sseg * 8;
  const size_t b_base = (size_t)(col0 + r_ld) * K + sseg * 8;
  _Float16* ldsA = As + wave * 512;
  _Float16* ldsB = Bs + wave * 512;
  const int swzA = quad ^ (m16 & 7);         // segment for kk=0 (c=quad)

  for (int k0 = 0; k0 < K; k0 += 64) {
#pragma unroll
    for (int i = 0; i < 4; ++i) {
      __builtin_amdgcn_global_load_lds(
          (const GLOBAL_AS void*)(A + a_base + (size_t)i * 32 * K + k0),
          (LDS_AS void*)(ldsA + i * 2048), 16, 0, 0);
      __builtin_amdgcn_global_load_lds(
          (const GLOBAL_AS void*)(B + b_base + (size_t)i * 32 * K + k0),
          (LDS_AS void*)(ldsB + i * 2048), 16, 0, 0);
    }
    __syncthreads();
#pragma unroll
    for (int kk = 0; kk < 2; ++kk) {
      const int swz = swzA ^ (kk * 4);
      half8_t af[4], bf[4];
#pragma unroll
      for (int i = 0; i < 4; ++i) {
        af[i] = *(half8_t*)&As[(wr * 64 + i * 16 + m16) * 64 + swz * 8];
        bf[i] = *(half8_t*)&Bs[(wc * 64 + i * 16 + m16) * 64 + swz * 8];
      }
#pragma unroll
      for (int i = 0; i < 4; ++i)
#pragma unroll
        for (int j = 0; j < 4; ++j)
          acc[i][j] = __builtin_amdgcn_mfma_f32_16x16x32_f16(af[i], bf[j], acc[i][j], 0, 0, 0);
    }
    __syncthreads();
  }

#pragma unroll
  for (int i = 0; i < 4; ++i)
#pragma unroll
    for (int j = 0; j < 4; ++j) {
      int col = col0 + wc * 64 + j * 16 + m16;
      int rowb = row0 + wr * 64 + i * 16 + quad * 4;
      half4_t hv = {(_Float16)acc[i][j][0], (_Float16)acc[i][j][1],
                    (_Float16)acc[i][j][2], (_Float16)acc[i][j][3]};
      if (col0 < 2048) {
#pragma unroll
        for (int r = 0; r < 4; ++r) qh[(size_t)(rowb + r) * DIMV + col] = hv[r];
      } else if (col0 < 3072) {
        *(half4_t*)&kT[(size_t)(col - 2048) * MTOK + rowb] = hv;
      } else {
        *(half4_t*)&vT[(size_t)(col - 3072) * MTOK + rowb] = hv;
      }
    }
}

// ---------------------------------------------------------------------------
// BK=64 swizzled GEMM, f32 output row-major: C = A[M,K] @ B[N,K]^T.
// ---------------------------------------------------------------------------
__global__ __launch_bounds__(256) void hgemm_bt64_f32(const _Float16* __restrict__ A,
                                                      const _Float16* __restrict__ B,
                                                      float* __restrict__ C,
                                                      int M, int N, int K) {
  __shared__ _Float16 As[128 * 64];
  __shared__ _Float16 Bs[128 * 64];
  const int tid = threadIdx.x;
  const int lane = tid & 63;
  const int wave = tid >> 6;
  const int row0 = blockIdx.y * 128, col0 = blockIdx.x * 128;
  const int wr = wave & 1, wc = wave >> 1;
  const int m16 = lane & 15, quad = lane >> 4;

  f32x4 acc[4][4];
#pragma unroll
  for (int i = 0; i < 4; ++i)
#pragma unroll
    for (int j = 0; j < 4; ++j) acc[i][j] = (f32x4){0.f, 0.f, 0.f, 0.f};

  const int r_ld = tid >> 3;
  const int sseg = (tid & 7) ^ (r_ld & 7);
  const size_t a_base = (size_t)(row0 + r_ld) * K + sseg * 8;
  const size_t b_base = (size_t)(col0 + r_ld) * K + sseg * 8;
  _Float16* ldsA = As + wave * 512;
  _Float16* ldsB = Bs + wave * 512;
  const int swzA = quad ^ (m16 & 7);

  for (int k0 = 0; k0 < K; k0 += 64) {
#pragma unroll
    for (int i = 0; i < 4; ++i) {
      __builtin_amdgcn_global_load_lds(
          (const GLOBAL_AS void*)(A + a_base + (size_t)i * 32 * K + k0),
          (LDS_AS void*)(ldsA + i * 2048), 16, 0, 0);
      __builtin_amdgcn_global_load_lds(
          (const GLOBAL_AS void*)(B + b_base + (size_t)i * 32 * K + k0),
          (LDS_AS void*)(ldsB + i * 2048), 16, 0, 0);
    }
    __syncthreads();
#pragma unroll
    for (int kk = 0; kk < 2; ++kk) {
      const int swz = swzA ^ (kk * 4);
      half8_t af[4], bf[4];
#pragma unroll
      for (int i = 0; i < 4; ++i) {
        af[i] = *(half8_t*)&As[(wr * 64 + i * 16 + m16) * 64 + swz * 8];
        bf[i] = *(half8_t*)&Bs[(wc * 64 + i * 16 + m16) * 64 + swz * 8];
      }
#pragma unroll
      for (int i = 0; i < 4; ++i)
#pragma unroll
        for (int j = 0; j < 4; ++j)
          acc[i][j] = __builtin_amdgcn_mfma_f32_16x16x32_f16(af[i], bf[j], acc[i][j], 0, 0, 0);
    }
    __syncthreads();
  }

#pragma unroll
  for (int i = 0; i < 4; ++i)
#pragma unroll
    for (int j = 0; j < 4; ++j) {
      int col = col0 + wc * 64 + j * 16 + m16;
      int rowb = row0 + wr * 64 + i * 16 + quad * 4;
#pragma unroll
      for (int r = 0; r < 4; ++r) C[(size_t)(rowb + r) * N + col] = acc[i][j][r];
    }
}

// ---------------------------------------------------------------------------
// RoPE + row softmax on q, fp16 in/out (f32 internally). Wave per (token,head).
// ---------------------------------------------------------------------------
__global__ __launch_bounds__(64) void rope_q_softmax_h(_Float16* __restrict__ q,
                                                       const float* __restrict__ fc) {
  int bi = blockIdx.x;
  int h = bi & (NHEAD - 1), m = bi >> 4;
  int s = m & (SEQ - 1);
  int t = threadIdx.x;
  size_t base = (size_t)m * DIMV + h * HD + 2 * t;
  half2_t xv = *(const half2_t*)&q[base];
  float2 cs = *(const float2*)&fc[s * HD + 2 * t];
  float x0 = (float)xv[0], x1 = (float)xv[1];
  float o0 = x0 * cs.x - x1 * cs.y;
  float o1 = x0 * cs.y + x1 * cs.x;
  const float sc = 0.08838834764831845f;  // 128^-0.5
  o0 *= sc; o1 *= sc;
  float mx = fmaxf(o0, o1);
#pragma unroll
  for (int off = 1; off < 64; off <<= 1) mx = fmaxf(mx, __shfl_xor(mx, off));
  float e0 = expf(o0 - mx), e1 = expf(o1 - mx);
  float sm = e0 + e1;
#pragma unroll
  for (int off = 1; off < 64; off <<= 1) sm += __shfl_xor(sm, off);
  float inv = 1.f / sm;
  half2_t ov = {(_Float16)(e0 * inv), (_Float16)(e1 * inv)};
  *(half2_t*)&q[base] = ov;
}

// ---------------------------------------------------------------------------
// RoPE + token-softmax on kT [1024 dims][4096 tokens] fp16, in place.
// ---------------------------------------------------------------------------
__global__ __launch_bounds__(256) void k_rope_softmax_T(_Float16* __restrict__ kT,
                                                        const float* __restrict__ fcT) {
  int bi = blockIdx.x;
  int b = bi & 1, pr = bi >> 1;
  int d0 = pr * 2, dl = d0 & 127;
  int t = threadIdx.x;
  size_t r0 = (size_t)d0 * MTOK + b * SEQ + t * 8;
  size_t r1 = r0 + MTOK;
  half8_t x0v = *(half8_t*)&kT[r0];
  half8_t x1v = *(half8_t*)&kT[r1];
  int s8 = t * 8;
  float4 ca = *(const float4*)&fcT[(size_t)dl * SEQ + s8];
  float4 cb = *(const float4*)&fcT[(size_t)dl * SEQ + s8 + 4];
  float4 sa = *(const float4*)&fcT[(size_t)(dl + 1) * SEQ + s8];
  float4 sb = *(const float4*)&fcT[(size_t)(dl + 1) * SEQ + s8 + 4];
  float cc[8] = {ca.x, ca.y, ca.z, ca.w, cb.x, cb.y, cb.z, cb.w};
  float ss[8] = {sa.x, sa.y, sa.z, sa.w, sb.x, sb.y, sb.z, sb.w};
  float e0[8], e1[8];
  float sum0 = 0.f, sum1 = 0.f;
#pragma unroll
  for (int j = 0; j < 8; ++j) {
    float x0 = (float)x0v[j], x1 = (float)x1v[j];
    float o0 = x0 * cc[j] - x1 * ss[j];
    float o1 = x0 * ss[j] + x1 * cc[j];
    e0[j] = expf(o0); e1[j] = expf(o1);
    sum0 += e0[j]; sum1 += e1[j];
  }
#pragma unroll
  for (int off = 1; off < 64; off <<= 1) {
    sum0 += __shfl_xor(sum0, off);
    sum1 += __shfl_xor(sum1, off);
  }
  __shared__ float red[8];
  if ((t & 63) == 0) { red[(t >> 6) * 2] = sum0; red[(t >> 6) * 2 + 1] = sum1; }
  __syncthreads();
  float S0 = red[0] + red[2] + red[4] + red[6];
  float S1 = red[1] + red[3] + red[5] + red[7];
  float i0 = 1.f / S0, i1 = 1.f / S1;
  half8_t w0, w1;
#pragma unroll
  for (int j = 0; j < 8; ++j) {
    w0[j] = (_Float16)(e0[j] * i0);
    w1[j] = (_Float16)(e1[j] * i1);
  }
  *(half8_t*)&kT[r0] = w0;
  *(half8_t*)&kT[r1] = w1;
}

// ---------------------------------------------------------------------------
// kT [1024][4096] -> kh [4096][1024]  (fp16 tile transpose)
// ---------------------------------------------------------------------------
__global__ __launch_bounds__(256) void transpose_k(const _Float16* __restrict__ kT,
                                                   _Float16* __restrict__ kh) {
  __shared__ _Float16 T[64][65];
  int t0 = blockIdx.x * 64, d0 = blockIdx.y * 64;
  int t = threadIdx.x;
  int r = t >> 3, c8 = (t & 7) * 8;
#pragma unroll
  for (int p = 0; p < 2; ++p) {
    int dr = p * 32 + r;
    half8_t v = *(const half8_t*)&kT[(size_t)(d0 + dr) * MTOK + t0 + c8];
#pragma unroll
    for (int j = 0; j < 8; ++j) T[c8 + j][dr] = v[j];
  }
  __syncthreads();
#pragma unroll
  for (int p = 0; p < 2; ++p) {
    int tr = p * 32 + r;
    half8_t v;
#pragma unroll
    for (int j = 0; j < 8; ++j) v[j] = T[tr][c8 + j];
    *(half8_t*)&kh[(size_t)(t0 + tr) * KVD + d0 + c8] = v;
  }
}

// ---------------------------------------------------------------------------
// kvT[e][d] = sum_c v[c,e]*k[c,d] per (b,kvh,chunk). MFMA fp16, M=N=K=128.
// ---------------------------------------------------------------------------
__global__ __launch_bounds__(256) void kv_chunk_mfma(const _Float16* __restrict__ vT,
                                                     const _Float16* __restrict__ kT,
                                                     float* __restrict__ kvT) {
  __shared__ _Float16 As[128 * 32];
  __shared__ _Float16 Bs[128 * 32];
  int bi = blockIdx.x;
  int n = bi & 15, kvh = (bi >> 4) & 7, b = bi >> 7;
  int tok0 = b * SEQ + n * CHUNK;
  const int tid = threadIdx.x;
  const int lane = tid & 63;
  const int wave = tid >> 6;
  const int wr = wave & 1, wc = wave >> 1;
  const int m16 = lane & 15, quad = lane >> 4;

  f32x4 acc[4][4];
#pragma unroll
  for (int i = 0; i < 4; ++i)
#pragma unroll
    for (int j = 0; j < 4; ++j) acc[i][j] = (f32x4){0.f, 0.f, 0.f, 0.f};

  const int r_ld = tid >> 2;
  const int seg = tid & 3;
  const size_t a_base = (size_t)(kvh * HD + r_ld) * MTOK + tok0 + seg * 8;
  const size_t b_base = a_base;
  _Float16* ldsA = As + wave * 512;
  _Float16* ldsB = Bs + wave * 512;

  for (int k0 = 0; k0 < 128; k0 += 32) {
#pragma unroll
    for (int i = 0; i < 2; ++i) {
      __builtin_amdgcn_global_load_lds(
          (const GLOBAL_AS void*)(vT + a_base + (size_t)i * 64 * MTOK + k0),
          (LDS_AS void*)(ldsA + i * 2048), 16, 0, 0);
      __builtin_amdgcn_global_load_lds(
          (const GLOBAL_AS void*)(kT + b_base + (size_t)i * 64 * MTOK + k0),
          (LDS_AS void*)(ldsB + i * 2048), 16, 0, 0);
    }
    __syncthreads();
    half8_t af[4], bf[4];
#pragma unroll
    for (int i = 0; i < 4; ++i) {
      af[i] = *(half8_t*)&As[(wr * 64 + i * 16 + m16) * 32 + quad * 8];
      bf[i] = *(half8_t*)&Bs[(wc * 64 + i * 16 + m16) * 32 + quad * 8];
    }
#pragma unroll
    for (int i = 0; i < 4; ++i)
#pragma unroll
      for (int j = 0; j < 4; ++j)
        acc[i][j] = __builtin_amdgcn_mfma_f32_16x16x32_f16(af[i], bf[j], acc[i][j], 0, 0, 0);
    __syncthreads();
  }
#pragma unroll
  for (int i = 0; i < 4; ++i)
#pragma unroll
    for (int j = 0; j < 4; ++j) {
      int col = wc * 64 + j * 16 + m16;
      int rowb = wr * 64 + i * 16 + quad * 4;
#pragma unroll
      for (int r = 0; r < 4; ++r)
        kvT[(size_t)bi * 16384 + (size_t)(rowb + r) * 128 + col] = acc[i][j][r];
    }
}

// ---------------------------------------------------------------------------
// Exclusive chunk-cumsum of kvT (f32), emitting fp16 cumT. grid 1024x256.
// ---------------------------------------------------------------------------
__global__ __launch_bounds__(256) void cumsum_h(const float* __restrict__ kvT,
                                                _Float16* __restrict__ cumh) {
  int gid = blockIdx.x * 256 + threadIdx.x;
  int bk = gid >> 14, idx = gid & 16383;
  size_t base = (size_t)bk * NCHUNK * 16384 + idx;
  float run = 0.f;
#pragma unroll
  for (int n = 0; n < NCHUNK; ++n) {
    cumh[base + (size_t)n * 16384] = (_Float16)run;
    run += kvT[base + (size_t)n * 16384];
  }
}

// ---------------------------------------------------------------------------
// Fused scores+output per (b,h,chunk): S = tril(q@k^T) -> LDS fp16;
// out = q@cumT + S@v, all fp16 MFMA, f32 accum. 512 blocks, 256 threads.
// ---------------------------------------------------------------------------
__global__ __launch_bounds__(256) void attn_fused(const _Float16* __restrict__ qh,
                                                  const _Float16* __restrict__ kh,
                                                  const _Float16* __restrict__ cumh,
                                                  const _Float16* __restrict__ vT,
                                                  _Float16* __restrict__ ath) {
  __shared__ _Float16 As[128 * 32];
  __shared__ _Float16 Bs[128 * 32];
  __shared__ _Float16 Ss[128][136];
  int bi = blockIdx.x;
  int n = bi & 15, h = (bi >> 4) & 15, b = bi >> 8;
  int kvh = h >> 1;
  int tok0 = b * SEQ + n * CHUNK;
  const int tid = threadIdx.x;
  const int lane = tid & 63;
  const int wave = tid >> 6;
  const int wr = wave & 1, wc = wave >> 1;
  const int m16 = lane & 15, quad = lane >> 4;
  const int r_ld = tid >> 2;
  const int seg = tid & 3;
  _Float16* ldsA = As + wave * 512;
  _Float16* ldsB = Bs + wave * 512;

  f32x4 acc[4][4];
#pragma unroll
  for (int i = 0; i < 4; ++i)
#pragma unroll
    for (int j = 0; j < 4; ++j) acc[i][j] = (f32x4){0.f, 0.f, 0.f, 0.f};

  const size_t qbase = (size_t)(tok0 + r_ld) * DIMV + h * HD + seg * 8;
  const size_t kbase = (size_t)(tok0 + r_ld) * KVD + kvh * HD + seg * 8;
  const size_t cbase = ((size_t)((b * 8 + kvh) * 16 + n)) * 16384 + (size_t)r_ld * 128 + seg * 8;
  const size_t vbase = (size_t)(kvh * HD + r_ld) * MTOK + tok0 + seg * 8;

  // ---- Phase A: S = q @ k^T over d ----
  for (int k0 = 0; k0 < 128; k0 += 32) {
#pragma unroll
    for (int i = 0; i < 2; ++i) {
      __builtin_amdgcn_global_load_lds(
          (const GLOBAL_AS void*)(qh + qbase + (size_t)i * 64 * DIMV + k0),
          (LDS_AS void*)(ldsA + i * 2048), 16, 0, 0);
      __builtin_amdgcn_global_load_lds(
          (const GLOBAL_AS void*)(kh + kbase + (size_t)i * 64 * KVD + k0),
          (LDS_AS void*)(ldsB + i * 2048), 16, 0, 0);
    }
    __syncthreads();
    half8_t af[4], bf[4];
#pragma unroll
    for (int i = 0; i < 4; ++i) {
      af[i] = *(half8_t*)&As[(wr * 64 + i * 16 + m16) * 32 + quad * 8];
      bf[i] = *(half8_t*)&Bs[(wc * 64 + i * 16 + m16) * 32 + quad * 8];
    }
#pragma unroll
    for (int i = 0; i < 4; ++i)
#pragma unroll
      for (int j = 0; j < 4; ++j)
        acc[i][j] = __builtin_amdgcn_mfma_f32_16x16x32_f16(af[i], bf[j], acc[i][j], 0, 0, 0);
    __syncthreads();
  }

#pragma unroll
  for (int i = 0; i < 4; ++i)
#pragma unroll
    for (int j = 0; j < 4; ++j) {
      int col = wc * 64 + j * 16 + m16;
      int rowb = wr * 64 + i * 16 + quad * 4;
#pragma unroll
      for (int r = 0; r < 4; ++r) {
        float v = (col <= rowb + r) ? acc[i][j][r] : 0.f;
        Ss[rowb + r][col] = (_Float16)v;
      }
      acc[i][j] = (f32x4){0.f, 0.f, 0.f, 0.f};
    }

  // ---- Phase B1 (inter): out += q @ cumT ----
  for (int ks = 0; ks < 4; ++ks) {
    int k0 = ks * 32;
#pragma unroll
    for (int i = 0; i < 2; ++i) {
      __builtin_amdgcn_global_load_lds(
          (const GLOBAL_AS void*)(qh + qbase + (size_t)i * 64 * DIMV + k0),
          (LDS_AS void*)(ldsA + i * 2048), 16, 0, 0);
      __builtin_amdgcn_global_load_lds(
          (const GLOBAL_AS void*)(cumh + cbase + (size_t)i * 64 * 128 + k0),
          (LDS_AS void*)(ldsB + i * 2048), 16, 0, 0);
    }
    __syncthreads();
    half8_t af[4], bf[4];
#pragma unroll
    for (int i = 0; i < 4; ++i) {
      af[i] = *(half8_t*)&As[(wr * 64 + i * 16 + m16) * 32 + quad * 8];
      bf[i] = *(half8_t*)&Bs[(wc * 64 + i * 16 + m16) * 32 + quad * 8];
    }
#pragma unroll
    for (int i = 0; i < 4; ++i)
#pragma unroll
      for (int j = 0; j < 4; ++j)
        acc[i][j] = __builtin_amdgcn_mfma_f32_16x16x32_f16(af[i], bf[j], acc[i][j], 0, 0, 0);
    __syncthreads();
  }

  // ---- Phase B2 (intra): out += S @ v ----
  for (int ks = 0; ks < 4; ++ks) {
    int k0 = ks * 32;
#pragma unroll
    for (int i = 0; i < 2; ++i) {
      __builtin_amdgcn_global_load_lds(
          (const GLOBAL_AS void*)(vT + vbase + (size_t)i * 64 * MTOK + k0),
          (LDS_AS void*)(ldsB + i * 2048), 16, 0, 0);
    }
    __syncthreads();
    half8_t af[4], bf[4];
#pragma unroll
    for (int i = 0; i < 4; ++i) {
      af[i] = *(half8_t*)&Ss[wr * 64 + i * 16 + m16][k0 + quad * 8];
      bf[i] = *(half8_t*)&Bs[(wc * 64 + i * 16 + m16) * 32 + quad * 8];
    }
#pragma unroll
    for (int i = 0; i < 4; ++i)
#pragma unroll
      for (int j = 0; j < 4; ++j)
        acc[i][j] = __builtin_amdgcn_mfma_f32_16x16x32_f16(af[i], bf[j], acc[i][j], 0, 0, 0);
    __syncthreads();
  }

#pragma unroll
  for (int i = 0; i < 4; ++i)
#pragma unroll
    for (int j = 0; j < 4; ++j) {
      int col = wc * 64 + j * 16 + m16;
      int rowb = wr * 64 + i * 16 + quad * 4;
#pragma unroll
      for (int r = 0; r < 4; ++r)
        ath[(size_t)(tok0 + rowb + r) * DIMV + h * HD + col] = (_Float16)acc[i][j][r];
    }
}

// ---------------------------------------------------------------------------
extern "C" void kernel_launch(void* const* d_in, const int* in_sizes, int n_in,
                              void* d_out, int out_size, void* d_ws, size_t ws_size,
                              hipStream_t stream) {
  const float* x  = (const float*)d_in[0];
  const float* fc = (const float*)d_in[1];
  const float* wq = (const float*)d_in[2];
  const float* wk = (const float*)d_in[3];
  const float* wv = (const float*)d_in[4];
  const float* wo = (const float*)d_in[5];
  float* out = (float*)d_out;

  char* p = (char*)d_ws;
  _Float16* xh    = (_Float16*)p;  p += 16777216;  // 4096x2048
  _Float16* wqkvh = (_Float16*)p;  p += 16777216;  // 4096x2048 (wq|wk|wv)
  _Float16* woh   = (_Float16*)p;  p += 8388608;   // 2048x2048
  _Float16* qh    = (_Float16*)p;  p += 16777216;  // 4096x2048
  _Float16* kT    = (_Float16*)p;  p += 8388608;   // 1024x4096
  _Float16* kh    = (_Float16*)p;  p += 8388608;   // 4096x1024
  _Float16* vT    = (_Float16*)p;  p += 8388608;   // 1024x4096
  float*    kvT   = (float*)p;     p += 16777216;  // 256x128x128 f32
  _Float16* cumh  = (_Float16*)p;  p += 8388608;
  _Float16* ath   = (_Float16*)p;  p += 16777216;  // 4096x2048
  float*    fcT   = (float*)p;     p += 1048576;   // 128x2048 f32

  // casts (wq|wk|wv concatenated into one [4096][2048] fp16 weight)
  cast_f2h<<<4096, 256, 0, stream>>>(x, xh, 8388608);
  cast_f2h<<<2048, 256, 0, stream>>>(wq, wqkvh, 4194304);
  cast_f2h<<<1024, 256, 0, stream>>>(wk, wqkvh + 4194304, 2097152);
  cast_f2h<<<1024, 256, 0, stream>>>(wv, wqkvh + 6291456, 2097152);
  cast_f2h<<<2048, 256, 0, stream>>>(wo, woh, 4194304);
  transpose_fc<<<dim3(32, 2), 256, 0, stream>>>(fc, fcT);

  // fused QKV projection (1024 blocks, swizzled BK=64)
  hgemm_qkv<<<dim3(32, 32), 256, 0, stream>>>(xh, wqkvh, qh, kT, vT);

  // rope + softmaxes
  rope_q_softmax_h<<<MTOK * NHEAD, 64, 0, stream>>>(qh, fc);
  k_rope_softmax_T<<<1024, 256, 0, stream>>>(kT, fcT);
  transpose_k<<<dim3(64, 16), 256, 0, stream>>>(kT, kh);

  // chunked linear attention (fp16 MFMA)
  kv_chunk_mfma<<<256, 256, 0, stream>>>(vT, kT, kvT);
  cumsum_h<<<1024, 256, 0, stream>>>(kvT, cumh);
  attn_fused<<<512, 256, 0, stream>>>(qh, kh, cumh, vT, ath);

  // output projection (swizzled BK=64)
  hgemm_bt64_f32<<<dim3(16, 32), 256, 0, stream>>>(ath, woh, out, MTOK, 2048, 2048);
}

// Round 6
// 300.816 us; speedup vs baseline: 5.5133x; 1.0499x over previous
//
#include <hip/hip_runtime.h>
#include <math.h>

#define DIMV 2048
#define NHEAD 16
#define NKV 8
#define HD 128
#define BATCH 2
#define SEQ 2048
#define CHUNK 128
#define NCHUNK 16
#define MTOK 4096  // BATCH*SEQ
#define KVD (NKV * HD)  // 1024

typedef _Float16 half8_t __attribute__((ext_vector_type(8)));
typedef _Float16 half4_t __attribute__((ext_vector_type(4)));
typedef _Float16 half2_t __attribute__((ext_vector_type(2)));
typedef float f32x4 __attribute__((ext_vector_type(4)));

#define GLOBAL_AS __attribute__((address_space(1)))
#define LDS_AS __attribute__((address_space(3)))

// ---------------------------------------------------------------------------
// All five f32->f16 casts in one launch. Ranges are multiples of 2048 elems,
// so the pointer selection is block-uniform. grid 10240 x 256.
// ---------------------------------------------------------------------------
__global__ __launch_bounds__(256) void cast_all(const float* __restrict__ x,
                                                const float* __restrict__ wq,
                                                const float* __restrict__ wk,
                                                const float* __restrict__ wv,
                                                const float* __restrict__ wo,
                                                _Float16* __restrict__ xh,
                                                _Float16* __restrict__ wqkvh,
                                                _Float16* __restrict__ woh) {
  long i = (long)(blockIdx.x * 256 + threadIdx.x) * 8;
  const float* src;
  _Float16* dst;
  long off;
  if (i < 8388608)        { src = x;  dst = xh;              off = 0; }
  else if (i < 12582912)  { src = wq; dst = wqkvh;           off = 8388608; }
  else if (i < 14680064)  { src = wk; dst = wqkvh + 4194304; off = 12582912; }
  else if (i < 16777216)  { src = wv; dst = wqkvh + 6291456; off = 14680064; }
  else                    { src = wo; dst = woh;             off = 16777216; }
  long e = i - off;
  float4 a = *(const float4*)&src[e];
  float4 b = *(const float4*)&src[e + 4];
  half8_t h = {(_Float16)a.x, (_Float16)a.y, (_Float16)a.z, (_Float16)a.w,
               (_Float16)b.x, (_Float16)b.y, (_Float16)b.z, (_Float16)b.w};
  *(half8_t*)&dst[e] = h;
}

// ---------------------------------------------------------------------------
// fc [2048][128] -> fcT [128][2048]   (f32, LDS tile transpose)
// ---------------------------------------------------------------------------
__global__ __launch_bounds__(256) void transpose_fc(const float* __restrict__ fc,
                                                    float* __restrict__ fcT) {
  __shared__ float T[64][65];
  int s0 = blockIdx.x * 64, d0 = blockIdx.y * 64;
  int t = threadIdx.x;
  int r = t >> 4, c4 = (t & 15) * 4;
#pragma unroll
  for (int p = 0; p < 4; ++p) {
    int sr = p * 16 + r;
    float4 v = *(const float4*)&fc[(size_t)(s0 + sr) * 128 + d0 + c4];
    T[sr][c4] = v.x; T[sr][c4 + 1] = v.y; T[sr][c4 + 2] = v.z; T[sr][c4 + 3] = v.w;
  }
  __syncthreads();
#pragma unroll
  for (int p = 0; p < 4; ++p) {
    int dr = p * 16 + r;
    float4 v = make_float4(T[c4][dr], T[c4 + 1][dr], T[c4 + 2][dr], T[c4 + 3][dr]);
    *(float4*)&fcT[(size_t)(d0 + dr) * SEQ + s0 + c4] = v;
  }
}

// ---------------------------------------------------------------------------
// Fused QKV projection: C[4096][4096] = xh @ wqkv^T. BK=64, XOR-swizzled LDS.
// Epilogue:
//   col0 <  2048 -> RoPE + row-softmax fused in-block, qh[tok][col] fp16
//   2048..3071   -> kT[col-2048][tok] fp16 (transposed)
//   3072..       -> vT[col-3072][tok] fp16 (transposed)
// grid dim3(32, 32). Each q-block covers exactly 128 tokens x 1 head.
// ---------------------------------------------------------------------------
__global__ __launch_bounds__(256) void hgemm_qkv(const _Float16* __restrict__ A,
                                                 const _Float16* __restrict__ B,
                                                 const float* __restrict__ fc,
                                                 _Float16* __restrict__ qh,
                                                 _Float16* __restrict__ kT,
                                                 _Float16* __restrict__ vT) {
  const int K = 2048;
  __shared__ _Float16 As[128 * 64];
  __shared__ _Float16 Bs[128 * 64];
  __shared__ float qsum[2][128];  // per-wc-row softmax partials (q path only)
  const int tid = threadIdx.x;
  const int lane = tid & 63;
  const int wave = tid >> 6;
  const int row0 = blockIdx.y * 128, col0 = blockIdx.x * 128;
  const int wr = wave & 1, wc = wave >> 1;
  const int m16 = lane & 15, quad = lane >> 4;

  f32x4 acc[4][4];
#pragma unroll
  for (int i = 0; i < 4; ++i)
#pragma unroll
    for (int j = 0; j < 4; ++j) acc[i][j] = (f32x4){0.f, 0.f, 0.f, 0.f};

  const int r_ld = tid >> 3;                 // 0..31
  const int sseg = (tid & 7) ^ (r_ld & 7);   // swizzled source segment
  const size_t a_base = (size_t)(row0 + r_ld) * K + sseg * 8;
  const size_t b_base = (size_t)(col0 + r_ld) * K + sseg * 8;
  _Float16* ldsA = As + wave * 512;
  _Float16* ldsB = Bs + wave * 512;
  const int swzA = quad ^ (m16 & 7);         // segment for kk=0 (c=quad)

  for (int k0 = 0; k0 < K; k0 += 64) {
#pragma unroll
    for (int i = 0; i < 4; ++i) {
      __builtin_amdgcn_global_load_lds(
          (const GLOBAL_AS void*)(A + a_base + (size_t)i * 32 * K + k0),
          (LDS_AS void*)(ldsA + i * 2048), 16, 0, 0);
      __builtin_amdgcn_global_load_lds(
          (const GLOBAL_AS void*)(B + b_base + (size_t)i * 32 * K + k0),
          (LDS_AS void*)(ldsB + i * 2048), 16, 0, 0);
    }
    __syncthreads();
#pragma unroll
    for (int kk = 0; kk < 2; ++kk) {
      const int swz = swzA ^ (kk * 4);
      half8_t af[4], bf[4];
#pragma unroll
      for (int i = 0; i < 4; ++i) {
        af[i] = *(half8_t*)&As[(wr * 64 + i * 16 + m16) * 64 + swz * 8];
        bf[i] = *(half8_t*)&Bs[(wc * 64 + i * 16 + m16) * 64 + swz * 8];
      }
#pragma unroll
      for (int i = 0; i < 4; ++i)
#pragma unroll
        for (int j = 0; j < 4; ++j)
          acc[i][j] = __builtin_amdgcn_mfma_f32_16x16x32_f16(af[i], bf[j], acc[i][j], 0, 0, 0);
    }
    __syncthreads();
  }

  if (col0 < 2048) {
    // ---- fused RoPE + row-softmax (head-dim) epilogue ----
    // C layout: col = wc*64 + j*16 + m16 (head-local dim), row = wr*64+i*16+quad*4+r.
    // RoPE pair (2t, 2t+1) = adjacent cols = adjacent m16 lanes -> shfl_xor 1.
    const float sc = 0.08838834764831845f;  // 128^-0.5
    float psum[4][4];
#pragma unroll
    for (int i = 0; i < 4; ++i)
#pragma unroll
      for (int r = 0; r < 4; ++r) psum[i][r] = 0.f;
#pragma unroll
    for (int i = 0; i < 4; ++i)
#pragma unroll
      for (int j = 0; j < 4; ++j) {
        int dl2 = (wc * 64 + j * 16 + m16) & ~1;  // even dim of the pair
#pragma unroll
        for (int r = 0; r < 4; ++r) {
          float val = acc[i][j][r];
          float par = __shfl_xor(val, 1);
          int s_tok = (row0 + wr * 64 + i * 16 + quad * 4 + r) & (SEQ - 1);
          float2 cs = *(const float2*)&fc[(size_t)s_tok * 128 + dl2];
          float o = val * cs.x + par * ((m16 & 1) ? cs.y : -cs.y);
          float e = __expf(o * sc);
          acc[i][j][r] = e;
          psum[i][r] += e;
        }
      }
    // reduce over the 16 m16 lanes (within quad group)
#pragma unroll
    for (int m = 1; m < 16; m <<= 1)
#pragma unroll
      for (int i = 0; i < 4; ++i)
#pragma unroll
        for (int r = 0; r < 4; ++r) psum[i][r] += __shfl_xor(psum[i][r], m);
    if (m16 == 0) {
#pragma unroll
      for (int i = 0; i < 4; ++i)
#pragma unroll
        for (int r = 0; r < 4; ++r)
          qsum[wc][wr * 64 + i * 16 + quad * 4 + r] = psum[i][r];
    }
    __syncthreads();
#pragma unroll
    for (int i = 0; i < 4; ++i)
#pragma unroll
      for (int r = 0; r < 4; ++r) {
        int rowl = wr * 64 + i * 16 + quad * 4 + r;
        psum[i][r] = 1.f / (qsum[0][rowl] + qsum[1][rowl]);
      }
#pragma unroll
    for (int i = 0; i < 4; ++i)
#pragma unroll
      for (int j = 0; j < 4; ++j) {
        int col = col0 + wc * 64 + j * 16 + m16;
#pragma unroll
        for (int r = 0; r < 4; ++r) {
          int row = row0 + wr * 64 + i * 16 + quad * 4 + r;
          qh[(size_t)row * DIMV + col] = (_Float16)(acc[i][j][r] * psum[i][r]);
        }
      }
  } else {
    // ---- k/v transposed epilogue ----
#pragma unroll
    for (int i = 0; i < 4; ++i)
#pragma unroll
      for (int j = 0; j < 4; ++j) {
        int col = col0 + wc * 64 + j * 16 + m16;
        int rowb = row0 + wr * 64 + i * 16 + quad * 4;
        half4_t hv = {(_Float16)acc[i][j][0], (_Float16)acc[i][j][1],
                      (_Float16)acc[i][j][2], (_Float16)acc[i][j][3]};
        if (col0 < 3072) {
          *(half4_t*)&kT[(size_t)(col - 2048) * MTOK + rowb] = hv;
        } else {
          *(half4_t*)&vT[(size_t)(col - 3072) * MTOK + rowb] = hv;
        }
      }
  }
}

// ---------------------------------------------------------------------------
// BK=64 swizzled GEMM, f32 output row-major: C = A[M,K] @ B[N,K]^T.
// ---------------------------------------------------------------------------
__global__ __launch_bounds__(256) void hgemm_bt64_f32(const _Float16* __restrict__ A,
                                                      const _Float16* __restrict__ B,
                                                      float* __restrict__ C,
                                                      int M, int N, int K) {
  __shared__ _Float16 As[128 * 64];
  __shared__ _Float16 Bs[128 * 64];
  const int tid = threadIdx.x;
  const int lane = tid & 63;
  const int wave = tid >> 6;
  const int row0 = blockIdx.y * 128, col0 = blockIdx.x * 128;
  const int wr = wave & 1, wc = wave >> 1;
  const int m16 = lane & 15, quad = lane >> 4;

  f32x4 acc[4][4];
#pragma unroll
  for (int i = 0; i < 4; ++i)
#pragma unroll
    for (int j = 0; j < 4; ++j) acc[i][j] = (f32x4){0.f, 0.f, 0.f, 0.f};

  const int r_ld = tid >> 3;
  const int sseg = (tid & 7) ^ (r_ld & 7);
  const size_t a_base = (size_t)(row0 + r_ld) * K + sseg * 8;
  const size_t b_base = (size_t)(col0 + r_ld) * K + sseg * 8;
  _Float16* ldsA = As + wave * 512;
  _Float16* ldsB = Bs + wave * 512;
  const int swzA = quad ^ (m16 & 7);

  for (int k0 = 0; k0 < K; k0 += 64) {
#pragma unroll
    for (int i = 0; i < 4; ++i) {
      __builtin_amdgcn_global_load_lds(
          (const GLOBAL_AS void*)(A + a_base + (size_t)i * 32 * K + k0),
          (LDS_AS void*)(ldsA + i * 2048), 16, 0, 0);
      __builtin_amdgcn_global_load_lds(
          (const GLOBAL_AS void*)(B + b_base + (size_t)i * 32 * K + k0),
          (LDS_AS void*)(ldsB + i * 2048), 16, 0, 0);
    }
    __syncthreads();
#pragma unroll
    for (int kk = 0; kk < 2; ++kk) {
      const int swz = swzA ^ (kk * 4);
      half8_t af[4], bf[4];
#pragma unroll
      for (int i = 0; i < 4; ++i) {
        af[i] = *(half8_t*)&As[(wr * 64 + i * 16 + m16) * 64 + swz * 8];
        bf[i] = *(half8_t*)&Bs[(wc * 64 + i * 16 + m16) * 64 + swz * 8];
      }
#pragma unroll
      for (int i = 0; i < 4; ++i)
#pragma unroll
        for (int j = 0; j < 4; ++j)
          acc[i][j] = __builtin_amdgcn_mfma_f32_16x16x32_f16(af[i], bf[j], acc[i][j], 0, 0, 0);
    }
    __syncthreads();
  }

#pragma unroll
  for (int i = 0; i < 4; ++i)
#pragma unroll
    for (int j = 0; j < 4; ++j) {
      int col = col0 + wc * 64 + j * 16 + m16;
      int rowb = row0 + wr * 64 + i * 16 + quad * 4;
#pragma unroll
      for (int r = 0; r < 4; ++r) C[(size_t)(rowb + r) * N + col] = acc[i][j][r];
    }
}

// ---------------------------------------------------------------------------
// RoPE + token-softmax on kT [1024 dims][4096 tokens] fp16, in place.
// ---------------------------------------------------------------------------
__global__ __launch_bounds__(256) void k_rope_softmax_T(_Float16* __restrict__ kT,
                                                        const float* __restrict__ fcT) {
  int bi = blockIdx.x;
  int b = bi & 1, pr = bi >> 1;
  int d0 = pr * 2, dl = d0 & 127;
  int t = threadIdx.x;
  size_t r0 = (size_t)d0 * MTOK + b * SEQ + t * 8;
  size_t r1 = r0 + MTOK;
  half8_t x0v = *(half8_t*)&kT[r0];
  half8_t x1v = *(half8_t*)&kT[r1];
  int s8 = t * 8;
  float4 ca = *(const float4*)&fcT[(size_t)dl * SEQ + s8];
  float4 cb = *(const float4*)&fcT[(size_t)dl * SEQ + s8 + 4];
  float4 sa = *(const float4*)&fcT[(size_t)(dl + 1) * SEQ + s8];
  float4 sb = *(const float4*)&fcT[(size_t)(dl + 1) * SEQ + s8 + 4];
  float cc[8] = {ca.x, ca.y, ca.z, ca.w, cb.x, cb.y, cb.z, cb.w};
  float ss[8] = {sa.x, sa.y, sa.z, sa.w, sb.x, sb.y, sb.z, sb.w};
  float e0[8], e1[8];
  float sum0 = 0.f, sum1 = 0.f;
#pragma unroll
  for (int j = 0; j < 8; ++j) {
    float x0 = (float)x0v[j], x1 = (float)x1v[j];
    float o0 = x0 * cc[j] - x1 * ss[j];
    float o1 = x0 * ss[j] + x1 * cc[j];
    e0[j] = expf(o0); e1[j] = expf(o1);
    sum0 += e0[j]; sum1 += e1[j];
  }
#pragma unroll
  for (int off = 1; off < 64; off <<= 1) {
    sum0 += __shfl_xor(sum0, off);
    sum1 += __shfl_xor(sum1, off);
  }
  __shared__ float red[8];
  if ((t & 63) == 0) { red[(t >> 6) * 2] = sum0; red[(t >> 6) * 2 + 1] = sum1; }
  __syncthreads();
  float S0 = red[0] + red[2] + red[4] + red[6];
  float S1 = red[1] + red[3] + red[5] + red[7];
  float i0 = 1.f / S0, i1 = 1.f / S1;
  half8_t w0, w1;
#pragma unroll
  for (int j = 0; j < 8; ++j) {
    w0[j] = (_Float16)(e0[j] * i0);
    w1[j] = (_Float16)(e1[j] * i1);
  }
  *(half8_t*)&kT[r0] = w0;
  *(half8_t*)&kT[r1] = w1;
}

// ---------------------------------------------------------------------------
// kT [1024][4096] -> kh [4096][1024]  (fp16 tile transpose)
// ---------------------------------------------------------------------------
__global__ __launch_bounds__(256) void transpose_k(const _Float16* __restrict__ kT,
                                                   _Float16* __restrict__ kh) {
  __shared__ _Float16 T[64][65];
  int t0 = blockIdx.x * 64, d0 = blockIdx.y * 64;
  int t = threadIdx.x;
  int r = t >> 3, c8 = (t & 7) * 8;
#pragma unroll
  for (int p = 0; p < 2; ++p) {
    int dr = p * 32 + r;
    half8_t v = *(const half8_t*)&kT[(size_t)(d0 + dr) * MTOK + t0 + c8];
#pragma unroll
    for (int j = 0; j < 8; ++j) T[c8 + j][dr] = v[j];
  }
  __syncthreads();
#pragma unroll
  for (int p = 0; p < 2; ++p) {
    int tr = p * 32 + r;
    half8_t v;
#pragma unroll
    for (int j = 0; j < 8; ++j) v[j] = T[tr][c8 + j];
    *(half8_t*)&kh[(size_t)(t0 + tr) * KVD + d0 + c8] = v;
  }
}

// ---------------------------------------------------------------------------
// kvT[e][d] = sum_c v[c,e]*k[c,d] per (b,kvh,chunk). MFMA fp16, M=N=K=128.
// ---------------------------------------------------------------------------
__global__ __launch_bounds__(256) void kv_chunk_mfma(const _Float16* __restrict__ vT,
                                                     const _Float16* __restrict__ kT,
                                                     float* __restrict__ kvT) {
  __shared__ _Float16 As[128 * 32];
  __shared__ _Float16 Bs[128 * 32];
  int bi = blockIdx.x;
  int n = bi & 15, kvh = (bi >> 4) & 7, b = bi >> 7;
  int tok0 = b * SEQ + n * CHUNK;
  const int tid = threadIdx.x;
  const int lane = tid & 63;
  const int wave = tid >> 6;
  const int wr = wave & 1, wc = wave >> 1;
  const int m16 = lane & 15, quad = lane >> 4;

  f32x4 acc[4][4];
#pragma unroll
  for (int i = 0; i < 4; ++i)
#pragma unroll
    for (int j = 0; j < 4; ++j) acc[i][j] = (f32x4){0.f, 0.f, 0.f, 0.f};

  const int r_ld = tid >> 2;
  const int seg = tid & 3;
  const size_t a_base = (size_t)(kvh * HD + r_ld) * MTOK + tok0 + seg * 8;
  const size_t b_base = a_base;
  _Float16* ldsA = As + wave * 512;
  _Float16* ldsB = Bs + wave * 512;

  for (int k0 = 0; k0 < 128; k0 += 32) {
#pragma unroll
    for (int i = 0; i < 2; ++i) {
      __builtin_amdgcn_global_load_lds(
          (const GLOBAL_AS void*)(vT + a_base + (size_t)i * 64 * MTOK + k0),
          (LDS_AS void*)(ldsA + i * 2048), 16, 0, 0);
      __builtin_amdgcn_global_load_lds(
          (const GLOBAL_AS void*)(kT + b_base + (size_t)i * 64 * MTOK + k0),
          (LDS_AS void*)(ldsB + i * 2048), 16, 0, 0);
    }
    __syncthreads();
    half8_t af[4], bf[4];
#pragma unroll
    for (int i = 0; i < 4; ++i) {
      af[i] = *(half8_t*)&As[(wr * 64 + i * 16 + m16) * 32 + quad * 8];
      bf[i] = *(half8_t*)&Bs[(wc * 64 + i * 16 + m16) * 32 + quad * 8];
    }
#pragma unroll
    for (int i = 0; i < 4; ++i)
#pragma unroll
      for (int j = 0; j < 4; ++j)
        acc[i][j] = __builtin_amdgcn_mfma_f32_16x16x32_f16(af[i], bf[j], acc[i][j], 0, 0, 0);
    __syncthreads();
  }
#pragma unroll
  for (int i = 0; i < 4; ++i)
#pragma unroll
    for (int j = 0; j < 4; ++j) {
      int col = wc * 64 + j * 16 + m16;
      int rowb = wr * 64 + i * 16 + quad * 4;
#pragma unroll
      for (int r = 0; r < 4; ++r)
        kvT[(size_t)bi * 16384 + (size_t)(rowb + r) * 128 + col] = acc[i][j][r];
    }
}

// ---------------------------------------------------------------------------
// Exclusive chunk-cumsum of kvT (f32), emitting fp16 cumT. grid 1024x256.
// ---------------------------------------------------------------------------
__global__ __launch_bounds__(256) void cumsum_h(const float* __restrict__ kvT,
                                                _Float16* __restrict__ cumh) {
  int gid = blockIdx.x * 256 + threadIdx.x;
  int bk = gid >> 14, idx = gid & 16383;
  size_t base = (size_t)bk * NCHUNK * 16384 + idx;
  float run = 0.f;
#pragma unroll
  for (int n = 0; n < NCHUNK; ++n) {
    cumh[base + (size_t)n * 16384] = (_Float16)run;
    run += kvT[base + (size_t)n * 16384];
  }
}

// ---------------------------------------------------------------------------
// Fused scores+output per (b,h,chunk): S = tril(q@k^T) -> LDS fp16;
// out = q@cumT + S@v, all fp16 MFMA, f32 accum. 512 blocks, 256 threads.
// ---------------------------------------------------------------------------
__global__ __launch_bounds__(256) void attn_fused(const _Float16* __restrict__ qh,
                                                  const _Float16* __restrict__ kh,
                                                  const _Float16* __restrict__ cumh,
                                                  const _Float16* __restrict__ vT,
                                                  _Float16* __restrict__ ath) {
  __shared__ _Float16 As[128 * 32];
  __shared__ _Float16 Bs[128 * 32];
  __shared__ _Float16 Ss[128][136];
  int bi = blockIdx.x;
  int n = bi & 15, h = (bi >> 4) & 15, b = bi >> 8;
  int kvh = h >> 1;
  int tok0 = b * SEQ + n * CHUNK;
  const int tid = threadIdx.x;
  const int lane = tid & 63;
  const int wave = tid >> 6;
  const int wr = wave & 1, wc = wave >> 1;
  const int m16 = lane & 15, quad = lane >> 4;
  const int r_ld = tid >> 2;
  const int seg = tid & 3;
  _Float16* ldsA = As + wave * 512;
  _Float16* ldsB = Bs + wave * 512;

  f32x4 acc[4][4];
#pragma unroll
  for (int i = 0; i < 4; ++i)
#pragma unroll
    for (int j = 0; j < 4; ++j) acc[i][j] = (f32x4){0.f, 0.f, 0.f, 0.f};

  const size_t qbase = (size_t)(tok0 + r_ld) * DIMV + h * HD + seg * 8;
  const size_t kbase = (size_t)(tok0 + r_ld) * KVD + kvh * HD + seg * 8;
  const size_t cbase = ((size_t)((b * 8 + kvh) * 16 + n)) * 16384 + (size_t)r_ld * 128 + seg * 8;
  const size_t vbase = (size_t)(kvh * HD + r_ld) * MTOK + tok0 + seg * 8;

  // ---- Phase A: S = q @ k^T over d ----
  for (int k0 = 0; k0 < 128; k0 += 32) {
#pragma unroll
    for (int i = 0; i < 2; ++i) {
      __builtin_amdgcn_global_load_lds(
          (const GLOBAL_AS void*)(qh + qbase + (size_t)i * 64 * DIMV + k0),
          (LDS_AS void*)(ldsA + i * 2048), 16, 0, 0);
      __builtin_amdgcn_global_load_lds(
          (const GLOBAL_AS void*)(kh + kbase + (size_t)i * 64 * KVD + k0),
          (LDS_AS void*)(ldsB + i * 2048), 16, 0, 0);
    }
    __syncthreads();
    half8_t af[4], bf[4];
#pragma unroll
    for (int i = 0; i < 4; ++i) {
      af[i] = *(half8_t*)&As[(wr * 64 + i * 16 + m16) * 32 + quad * 8];
      bf[i] = *(half8_t*)&Bs[(wc * 64 + i * 16 + m16) * 32 + quad * 8];
    }
#pragma unroll
    for (int i = 0; i < 4; ++i)
#pragma unroll
      for (int j = 0; j < 4; ++j)
        acc[i][j] = __builtin_amdgcn_mfma_f32_16x16x32_f16(af[i], bf[j], acc[i][j], 0, 0, 0);
    __syncthreads();
  }

#pragma unroll
  for (int i = 0; i < 4; ++i)
#pragma unroll
    for (int j = 0; j < 4; ++j) {
      int col = wc * 64 + j * 16 + m16;
      int rowb = wr * 64 + i * 16 + quad * 4;
#pragma unroll
      for (int r = 0; r < 4; ++r) {
        float v = (col <= rowb + r) ? acc[i][j][r] : 0.f;
        Ss[rowb + r][col] = (_Float16)v;
      }
      acc[i][j] = (f32x4){0.f, 0.f, 0.f, 0.f};
    }

  // ---- Phase B1 (inter): out += q @ cumT ----
  for (int ks = 0; ks < 4; ++ks) {
    int k0 = ks * 32;
#pragma unroll
    for (int i = 0; i < 2; ++i) {
      __builtin_amdgcn_global_load_lds(
          (const GLOBAL_AS void*)(qh + qbase + (size_t)i * 64 * DIMV + k0),
          (LDS_AS void*)(ldsA + i * 2048), 16, 0, 0);
      __builtin_amdgcn_global_load_lds(
          (const GLOBAL_AS void*)(cumh + cbase + (size_t)i * 64 * 128 + k0),
          (LDS_AS void*)(ldsB + i * 2048), 16, 0, 0);
    }
    __syncthreads();
    half8_t af[4], bf[4];
#pragma unroll
    for (int i = 0; i < 4; ++i) {
      af[i] = *(half8_t*)&As[(wr * 64 + i * 16 + m16) * 32 + quad * 8];
      bf[i] = *(half8_t*)&Bs[(wc * 64 + i * 16 + m16) * 32 + quad * 8];
    }
#pragma unroll
    for (int i = 0; i < 4; ++i)
#pragma unroll
      for (int j = 0; j < 4; ++j)
        acc[i][j] = __builtin_amdgcn_mfma_f32_16x16x32_f16(af[i], bf[j], acc[i][j], 0, 0, 0);
    __syncthreads();
  }

  // ---- Phase B2 (intra): out += S @ v ----
  for (int ks = 0; ks < 4; ++ks) {
    int k0 = ks * 32;
#pragma unroll
    for (int i = 0; i < 2; ++i) {
      __builtin_amdgcn_global_load_lds(
          (const GLOBAL_AS void*)(vT + vbase + (size_t)i * 64 * MTOK + k0),
          (LDS_AS void*)(ldsB + i * 2048), 16, 0, 0);
    }
    __syncthreads();
    half8_t af[4], bf[4];
#pragma unroll
    for (int i = 0; i < 4; ++i) {
      af[i] = *(half8_t*)&Ss[wr * 64 + i * 16 + m16][k0 + quad * 8];
      bf[i] = *(half8_t*)&Bs[(wc * 64 + i * 16 + m16) * 32 + quad * 8];
    }
#pragma unroll
    for (int i = 0; i < 4; ++i)
#pragma unroll
      for (int j = 0; j < 4; ++j)
        acc[i][j] = __builtin_amdgcn_mfma_f32_16x16x32_f16(af[i], bf[j], acc[i][j], 0, 0, 0);
    __syncthreads();
  }

#pragma unroll
  for (int i = 0; i < 4; ++i)
#pragma unroll
    for (int j = 0; j < 4; ++j) {
      int col = wc * 64 + j * 16 + m16;
      int rowb = wr * 64 + i * 16 + quad * 4;
#pragma unroll
      for (int r = 0; r < 4; ++r)
        ath[(size_t)(tok0 + rowb + r) * DIMV + h * HD + col] = (_Float16)acc[i][j][r];
    }
}

// ---------------------------------------------------------------------------
extern "C" void kernel_launch(void* const* d_in, const int* in_sizes, int n_in,
                              void* d_out, int out_size, void* d_ws, size_t ws_size,
                              hipStream_t stream) {
  const float* x  = (const float*)d_in[0];
  const float* fc = (const float*)d_in[1];
  const float* wq = (const float*)d_in[2];
  const float* wk = (const float*)d_in[3];
  const float* wv = (const float*)d_in[4];
  const float* wo = (const float*)d_in[5];
  float* out = (float*)d_out;

  char* p = (char*)d_ws;
  _Float16* xh    = (_Float16*)p;  p += 16777216;  // 4096x2048
  _Float16* wqkvh = (_Float16*)p;  p += 16777216;  // 4096x2048 (wq|wk|wv)
  _Float16* woh   = (_Float16*)p;  p += 8388608;   // 2048x2048
  _Float16* qh    = (_Float16*)p;  p += 16777216;  // 4096x2048
  _Float16* kT    = (_Float16*)p;  p += 8388608;   // 1024x4096
  _Float16* kh    = (_Float16*)p;  p += 8388608;   // 4096x1024
  _Float16* vT    = (_Float16*)p;  p += 8388608;   // 1024x4096
  float*    kvT   = (float*)p;     p += 16777216;  // 256x128x128 f32
  _Float16* cumh  = (_Float16*)p;  p += 8388608;
  _Float16* ath   = (_Float16*)p;  p += 16777216;  // 4096x2048
  float*    fcT   = (float*)p;     p += 1048576;   // 128x2048 f32

  // all casts in one launch
  cast_all<<<10240, 256, 0, stream>>>(x, wq, wk, wv, wo, xh, wqkvh, woh);
  transpose_fc<<<dim3(32, 2), 256, 0, stream>>>(fc, fcT);

  // fused QKV projection + q RoPE/softmax (1024 blocks, swizzled BK=64)
  hgemm_qkv<<<dim3(32, 32), 256, 0, stream>>>(xh, wqkvh, fc, qh, kT, vT);

  // k rope + softmax, then transpose to token-major
  k_rope_softmax_T<<<1024, 256, 0, stream>>>(kT, fcT);
  transpose_k<<<dim3(64, 16), 256, 0, stream>>>(kT, kh);

  // chunked linear attention (fp16 MFMA)
  kv_chunk_mfma<<<256, 256, 0, stream>>>(vT, kT, kvT);
  cumsum_h<<<1024, 256, 0, stream>>>(kvT, cumh);
  attn_fused<<<512, 256, 0, stream>>>(qh, kh, cumh, vT, ath);

  // output projection (swizzled BK=64)
  hgemm_bt64_f32<<<dim3(16, 32), 256, 0, stream>>>(ath, woh, out, MTOK, 2048, 2048);
}